// Round 7
// baseline (340.061 us; speedup 1.0000x reference)
//
#include <hip/hip_runtime.h>
#include <hip/hip_fp16.h>
#include <cmath>
#include <cstdint>

// Problem constants (fixed by the reference).
constexpr int P  = 2000, M = 150, DG = 2000, F = 256, H = 4, DH = 64;
constexpr int N1 = P + M;          // 2150
constexpr int N2 = P + DG;         // 4000
constexpr int E1 = 137600, E2 = 256000, EGP = 64000, EGM = 4800;
constexpr int SA_HID = 128;

// Edge-range offsets for the fused build kernel.
constexpr int HO1 = E1, HO2 = E1 + E2, HO3 = HO2 + EGP, HO4 = HO3 + EGP,
              HO5 = HO4 + EGM, HOE = HO5 + EGM;   // 531200 total edges

// ELL capacities (overflow list guarantees correctness regardless).
constexpr int CAP_A = 160;
constexpr int CAP_G = 96;
constexpr int OVF_CAP = 4096;

// One counter per 64B line (R7: removed same-line atomic serialization).
constexpr int CPAD = 16;

// ---- fp16 helpers -----------------------------------------------------------
__device__ __forceinline__ float4 h4_to_f4(const __half* p) {
  union { ushort4 u4; __half2 h2[2]; } u;
  u.u4 = *(const ushort4*)p;
  float2 lo = __half22float2(u.h2[0]);
  float2 hi = __half22float2(u.h2[1]);
  return make_float4(lo.x, lo.y, hi.x, hi.y);
}
__device__ __forceinline__ void f4_to_h4(__half* p, float4 v) {
  union { ushort4 u4; __half2 h2[2]; } u;
  u.h2[0] = __float22half2_rn(make_float2(v.x, v.y));
  u.h2[1] = __float22half2_rn(make_float2(v.z, v.w));
  *(ushort4*)p = u.u4;
}
// 16B load: 8 halves -> two float4 (R6: 2 edges per gather instruction).
__device__ __forceinline__ void h8_to_f8(const __half* p, float4& lo, float4& hi) {
  union { uint4 u; __half2 h2[4]; } uu;
  uu.u = *(const uint4*)p;
  float2 a0 = __half22float2(uu.h2[0]);
  float2 a1 = __half22float2(uu.h2[1]);
  float2 a2 = __half22float2(uu.h2[2]);
  float2 a3 = __half22float2(uu.h2[3]);
  lo = make_float4(a0.x, a0.y, a1.x, a1.y);
  hi = make_float4(a2.x, a2.y, a3.x, a3.y);
}

// ---------------------------------------------------------------------------
// ELL build (padded counters) + fused fp32->fp16 embed cast.
// ---------------------------------------------------------------------------
constexpr int CAST_CH = (P * F + M * F + DG * F) / 8;   // 8-float chunks

__global__ __launch_bounds__(256) void k_build(
    const int* __restrict__ a1r, const int* __restrict__ a1c, const float* __restrict__ a1v,
    const int* __restrict__ a2r, const int* __restrict__ a2c, const float* __restrict__ a2v,
    const int* __restrict__ d0, const int* __restrict__ s0,
    const int* __restrict__ d1, const int* __restrict__ s1,
    const int* __restrict__ d2, const int* __restrict__ s2,
    const int* __restrict__ d3, const int* __restrict__ s3,
    int* cur1, uint2* ell1, int* cur2, uint2* ell2,
    int* cu0, unsigned* eg0, int* cu1, unsigned* eg1,
    int* cu2, unsigned* eg2, int* cu3, unsigned* eg3,
    int* __restrict__ ovf_n, int4* __restrict__ ovf,
    const float* __restrict__ pEf, const float* __restrict__ mEf,
    const float* __restrict__ dEf,
    __half* __restrict__ pEh, __half* __restrict__ mEh, __half* __restrict__ dEh) {
  int tid = blockIdx.x * 256 + threadIdx.x;
  int T = gridDim.x * 256;
  int seg[4], row[4]; unsigned p0[4], p1[4];
#pragma unroll
  for (int u = 0; u < 4; ++u) {
    int i = tid + u * T;
    seg[u] = -1;
    if (i < HOE) {
      if (i < HO1)      { seg[u] = 0; row[u] = a1r[i]; p0[u] = (unsigned)a1c[i]; p1[u] = __float_as_uint(a1v[i]); }
      else if (i < HO2) { int j = i - HO1; seg[u] = 1; row[u] = a2r[j]; p0[u] = (unsigned)a2c[j]; p1[u] = __float_as_uint(a2v[j]); }
      else if (i < HO3) { int j = i - HO2; seg[u] = 2; row[u] = d0[j]; p0[u] = (unsigned)s0[j]; }
      else if (i < HO4) { int j = i - HO3; seg[u] = 3; row[u] = d1[j]; p0[u] = (unsigned)s1[j]; }
      else if (i < HO5) { int j = i - HO4; seg[u] = 4; row[u] = d2[j]; p0[u] = (unsigned)s2[j]; }
      else              { int j = i - HO5; seg[u] = 5; row[u] = d3[j]; p0[u] = (unsigned)s3[j]; }
    }
  }
#pragma unroll
  for (int u = 0; u < 4; ++u) {
    int r = row[u];
    switch (seg[u]) {
      case 0: { int slot = atomicAdd(&cur1[(size_t)r * CPAD], 1);
        if (slot < CAP_A) ell1[(size_t)r * CAP_A + slot] = make_uint2(p0[u], p1[u]);
        else { int o = atomicAdd(&ovf_n[0], 1); if (o < OVF_CAP) ovf[0 * OVF_CAP + o] = make_int4(r, (int)p0[u], (int)p1[u], 0); } } break;
      case 1: { int slot = atomicAdd(&cur2[(size_t)r * CPAD], 1);
        if (slot < CAP_A) ell2[(size_t)r * CAP_A + slot] = make_uint2(p0[u], p1[u]);
        else { int o = atomicAdd(&ovf_n[1], 1); if (o < OVF_CAP) ovf[1 * OVF_CAP + o] = make_int4(r, (int)p0[u], (int)p1[u], 0); } } break;
      case 2: { int slot = atomicAdd(&cu0[(size_t)r * CPAD], 1);
        if (slot < CAP_G) eg0[(size_t)r * CAP_G + slot] = p0[u];
        else { int o = atomicAdd(&ovf_n[2], 1); if (o < OVF_CAP) ovf[2 * OVF_CAP + o] = make_int4(r, (int)p0[u], 0, 0); } } break;
      case 3: { int slot = atomicAdd(&cu1[(size_t)r * CPAD], 1);
        if (slot < CAP_G) eg1[(size_t)r * CAP_G + slot] = p0[u];
        else { int o = atomicAdd(&ovf_n[3], 1); if (o < OVF_CAP) ovf[3 * OVF_CAP + o] = make_int4(r, (int)p0[u], 0, 0); } } break;
      case 4: { int slot = atomicAdd(&cu2[(size_t)r * CPAD], 1);
        if (slot < CAP_G) eg2[(size_t)r * CAP_G + slot] = p0[u];
        else { int o = atomicAdd(&ovf_n[4], 1); if (o < OVF_CAP) ovf[4 * OVF_CAP + o] = make_int4(r, (int)p0[u], 0, 0); } } break;
      case 5: { int slot = atomicAdd(&cu3[(size_t)r * CPAD], 1);
        if (slot < CAP_G) eg3[(size_t)r * CAP_G + slot] = p0[u];
        else { int o = atomicAdd(&ovf_n[5], 1); if (o < OVF_CAP) ovf[5 * OVF_CAP + o] = make_int4(r, (int)p0[u], 0, 0); } } break;
      default: break;
    }
  }
  // Fused embed cast fp32 -> fp16 (independent streaming work).
  for (int c = tid; c < CAST_CH; c += T) {
    int j = c * 8;
    const float* src; __half* dst;
    if (j < P * F)              { src = pEf + j;               dst = pEh + j; }
    else if (j < P * F + M * F) { src = mEf + (j - P * F);     dst = mEh + (j - P * F); }
    else                        { src = dEf + (j - P*F - M*F); dst = dEh + (j - P*F - M*F); }
    float4 a = *(const float4*)src, b = *(const float4*)(src + 4);
    f4_to_h4(dst, a);
    f4_to_h4(dst + 4, b);
  }
}

// ---------------------------------------------------------------------------
// SPMM (R6): TWO waves per row (edge parity) x TWO half-waves per edge-pair.
// Lanes 0-31 gather edge A, lanes 32-63 edge B, 16B/lane (uint4) -> 2 edges
// per memory instruction, 8 floats/lane accumulator, shfl_down(32) combine.
// Odd tail handled with a weight-0 dummy edge (col 0).
// ---------------------------------------------------------------------------
template<int LAYER>
__global__ __launch_bounds__(256) void k_spmm(
    const int* __restrict__ cur1, const uint2* __restrict__ ell1,
    const int* __restrict__ cur2, const uint2* __restrict__ ell2,
    const int* __restrict__ ovf_n, const int4* __restrict__ ovf,
    const __half* __restrict__ pEh, const __half* __restrict__ mEh,
    const __half* __restrict__ dEh,
    float* __restrict__ lat1f, float* __restrict__ lat2f,
    __half* __restrict__ lat1h, __half* __restrict__ lat2h,
    float* __restrict__ acc1, float* __restrict__ acc2,
    float* __restrict__ out_mgcn, float* __restrict__ out_dgcn) {
  int grp = (blockIdx.x * 256 + threadIdx.x) >> 7;   // row-group id
  int lane = threadIdx.x & 63;
  int wh   = (threadIdx.x >> 6) & 1;                 // wave-half within group
  int gl   = threadIdx.x >> 7;                       // group slot in block (0/1)
  int half = lane >> 5;                              // edge-slot within pair
  int hl   = lane & 31;
  int fo8  = hl << 3;                                // 8-float feature offset
  bool g2 = grp >= N1;
  int row = g2 ? grp - N1 : grp;
  const uint2* pe = (g2 ? ell2 : ell1) + (size_t)row * CAP_A;
  const __half* latinh = g2 ? lat2h : lat1h;
  const __half* tailEh = g2 ? dEh : mEh;
  int deg = (g2 ? cur2 : cur1)[(size_t)row * CPAD];
  int dn = deg < CAP_A ? deg : CAP_A;
  float4 sA = {0.f, 0.f, 0.f, 0.f}, sB = {0.f, 0.f, 0.f, 0.f};
  auto base = [&](int c) -> const __half* {
    if (LAYER == 1) return (c < P) ? (pEh + (size_t)c * F) : (tailEh + (size_t)(c - P) * F);
    return latinh + (size_t)c * F;
  };
  auto fetch8 = [&](int c, float4& lo, float4& hi) {
    h8_to_f8(base(c) + fo8, lo, hi);
  };
  int i = wh;
  for (; i + 15 <= dn; i += 16) {    // 8 edges, 4 gather instructions
    uint2 m[8];
#pragma unroll
    for (int u = 0; u < 8; ++u) m[u] = pe[i + 2 * u];
    float4 lo[4], hi[4];
#pragma unroll
    for (int u = 0; u < 4; ++u) {
      uint2 me = half ? m[2 * u + 1] : m[2 * u];
      fetch8((int)me.x, lo[u], hi[u]);
    }
#pragma unroll
    for (int u = 0; u < 4; ++u) {
      uint2 me = half ? m[2 * u + 1] : m[2 * u];
      float v = __uint_as_float(me.y);
      sA.x += v * lo[u].x; sA.y += v * lo[u].y; sA.z += v * lo[u].z; sA.w += v * lo[u].w;
      sB.x += v * hi[u].x; sB.y += v * hi[u].y; sB.z += v * hi[u].z; sB.w += v * hi[u].w;
    }
  }
  for (; i + 3 <= dn; i += 4) {      // 2 edges, 1 gather instruction
    uint2 m0 = pe[i], m1 = pe[i + 2];
    uint2 me = half ? m1 : m0;
    float4 lo, hi; fetch8((int)me.x, lo, hi);
    float v = __uint_as_float(me.y);
    sA.x += v * lo.x; sA.y += v * lo.y; sA.z += v * lo.z; sA.w += v * lo.w;
    sB.x += v * hi.x; sB.y += v * hi.y; sB.z += v * hi.z; sB.w += v * hi.w;
  }
  if (i < dn) {                      // 1 edge left: dummy (col 0, w=0) on high half
    uint2 m0 = pe[i];
    uint2 me = half ? make_uint2(0u, 0u) : m0;
    float4 lo, hi; fetch8((int)me.x, lo, hi);
    float v = __uint_as_float(me.y);
    sA.x += v * lo.x; sA.y += v * lo.y; sA.z += v * lo.z; sA.w += v * lo.w;
    sB.x += v * hi.x; sB.y += v * hi.y; sB.z += v * hi.z; sB.w += v * hi.w;
  }
  // combine high half -> low half within the wave
  sA.x += __shfl_down(sA.x, 32, 64); sA.y += __shfl_down(sA.y, 32, 64);
  sA.z += __shfl_down(sA.z, 32, 64); sA.w += __shfl_down(sA.w, 32, 64);
  sB.x += __shfl_down(sB.x, 32, 64); sB.y += __shfl_down(sB.y, 32, 64);
  sB.z += __shfl_down(sB.z, 32, 64); sB.w += __shfl_down(sB.w, 32, 64);
  __shared__ float part[2][F];
  if (wh == 1 && half == 0) {
    *(float4*)&part[gl][fo8]     = sA;
    *(float4*)&part[gl][fo8 + 4] = sB;
  }
  __syncthreads();
  if (wh == 1) return;
  if (half == 0) {
    float4 pa = *(const float4*)&part[gl][fo8];
    float4 pb = *(const float4*)&part[gl][fo8 + 4];
    sA.x += pa.x; sA.y += pa.y; sA.z += pa.z; sA.w += pa.w;
    sB.x += pb.x; sB.y += pb.y; sB.z += pb.z; sB.w += pb.w;
  }
  // Overflow edges (normally zero): processed by all lanes (low half accumulates).
  {
    int gi = g2 ? 1 : 0;
    int on = ovf_n[gi];
    if (on > 0) {
      const int4* ol = ovf + gi * OVF_CAP;
      for (int k = 0; k < on; ++k) {
        int4 e = ol[k];
        if (e.x == row) {
          float v = __int_as_float(e.z);
          float4 lo, hi; fetch8(e.y, lo, hi);
          sA.x += v * lo.x; sA.y += v * lo.y; sA.z += v * lo.z; sA.w += v * lo.w;
          sB.x += v * hi.x; sB.y += v * hi.y; sB.z += v * hi.z; sB.w += v * hi.w;
        }
      }
    }
  }
  if (half != 0) return;             // only low half writes outputs
  float4 lA, lB;
  lA.x = sA.x > 0.f ? sA.x : 0.5f * sA.x;
  lA.y = sA.y > 0.f ? sA.y : 0.5f * sA.y;
  lA.z = sA.z > 0.f ? sA.z : 0.5f * sA.z;
  lA.w = sA.w > 0.f ? sA.w : 0.5f * sA.w;
  lB.x = sB.x > 0.f ? sB.x : 0.5f * sB.x;
  lB.y = sB.y > 0.f ? sB.y : 0.5f * sB.y;
  lB.z = sB.z > 0.f ? sB.z : 0.5f * sB.z;
  lB.w = sB.w > 0.f ? sB.w : 0.5f * sB.w;
  size_t off = (size_t)row * F + fo8;
  if (LAYER == 1) {
    float* lf = (g2 ? lat2f : lat1f);
    *(float4*)(lf + off) = lA;
    *(float4*)(lf + off + 4) = lB;
    __half* lh = (g2 ? lat2h : lat1h);
    f4_to_h4(lh + off, lA);
    f4_to_h4(lh + off + 4, lB);
  } else {
    const float* latf = g2 ? lat2f : lat1f;
    float4 b0 = *(const float4*)(latf + off);
    float4 b1 = *(const float4*)(latf + off + 4);
    float4 a0 = {b0.x + lA.x, b0.y + lA.y, b0.z + lA.z, b0.w + lA.w};
    float4 a1 = {b1.x + lB.x, b1.y + lB.y, b1.z + lB.z, b1.w + lB.w};
    float* ac = (g2 ? acc2 : acc1);
    *(float4*)(ac + off) = a0;
    *(float4*)(ac + off + 4) = a1;
    if (row >= P) {
      float* og = (g2 ? out_dgcn : out_mgcn);
      size_t ooff = (size_t)(row - P) * F + fo8;
      *(float4*)(og + ooff) = a0;
      *(float4*)(og + ooff + 4) = a1;
    }
  }
}

// ---------------------------------------------------------------------------
// All 4 GAT feature GEMMs. FR=8 (R8/R9: occupancy beats W-traffic reduction).
// ---------------------------------------------------------------------------
constexpr int FR  = 8;
constexpr int NB0 = (P + FR - 1) / FR;   // 250
constexpr int NB2 = (M + FR - 1) / FR;   // 19
constexpr int FEAT_BLOCKS = 2 * NB0 + 2 * NB2;

__global__ __launch_bounds__(256) void k_gat_feat_all(
    const float* __restrict__ acc1, const float* __restrict__ acc2,
    const float* __restrict__ gat_W, const float* __restrict__ gat_al,
    const float* __restrict__ gat_ar,
    __half* __restrict__ f0, __half* __restrict__ f1,
    __half* __restrict__ f2, __half* __restrict__ f3,
    float* __restrict__ el, float* __restrict__ er) {
  int b = blockIdx.x;
  int g, rb, n; const float* h; __half* fout;
  if (b < NB0)            { g = 0; rb = b;              n = P; h = acc1; fout = f0; }
  else if (b < 2 * NB0)   { g = 1; rb = b - NB0;        n = P; h = acc2; fout = f1; }
  else if (b < 2*NB0+NB2) { g = 2; rb = b - 2 * NB0;    n = M; h = acc1 + (size_t)P * F; fout = f2; }
  else                    { g = 3; rb = b - 2*NB0 - NB2; n = M; h = acc1 + (size_t)P * F; fout = f3; }
  int elo = (g == 0) ? 0 : (g == 1) ? P * H : (g == 2) ? 2 * P * H : (2 * P + M) * H;
  const float* W = gat_W + (size_t)g * F * F;
  __shared__ float hs[FR][F];
  int t = threadIdx.x;
  int r0 = rb * FR;
  for (int q = t; q < FR * 64; q += 256) {
    int r = q >> 6, ln = q & 63;
    int row = r0 + r;
    float4 v = {0.f, 0.f, 0.f, 0.f};
    if (row < n) v = *(const float4*)(h + (size_t)row * F + (ln << 2));
    *(float4*)&hs[r][ln << 2] = v;
  }
  __syncthreads();
  float acc[FR];
#pragma unroll
  for (int r = 0; r < FR; ++r) acc[r] = 0.f;
  for (int k = 0; k < F; k += 4) {
    float w0 = W[(size_t)k * F + t],       w1 = W[(size_t)(k + 1) * F + t],
          w2 = W[(size_t)(k + 2) * F + t], w3 = W[(size_t)(k + 3) * F + t];
#pragma unroll
    for (int r = 0; r < FR; ++r) {
      float4 h4 = *(const float4*)&hs[r][k];
      acc[r] += h4.x * w0 + h4.y * w1 + h4.z * w2 + h4.w * w3;
    }
  }
  int head = t >> 6, d = t & 63;           // one wave == one head
  float av = gat_al[g * H * DH + head * DH + d];
  float rv = gat_ar[g * H * DH + head * DH + d];
#pragma unroll
  for (int r = 0; r < FR; ++r) {
    int row = r0 + r;
    if (row < n) {
      fout[(size_t)row * F + t] = __float2half_rn(acc[r]);
      float cl = acc[r] * av, cr = acc[r] * rv;
      for (int o = 32; o > 0; o >>= 1) {
        cl += __shfl_down(cl, o, 64);
        cr += __shfl_down(cr, o, 64);
      }
      if (d == 0) { el[elo + row * H + head] = cl; er[elo + row * H + head] = cr; }
    }
  }
}

// ---------------------------------------------------------------------------
// All 4 GAT aggregations (R6): SINGLE-PASS online softmax (running m/ssum/acc
// with exp(m_old-m_new) rescale) — removes the separate max pass (~half the
// edge score gathers) and one LDS barrier round. 2 waves/row parity split.
// ---------------------------------------------------------------------------
__global__ __launch_bounds__(256) void k_gat_agg_all(
    const int* __restrict__ cu0, const unsigned* __restrict__ eg0,
    const int* __restrict__ cu1, const unsigned* __restrict__ eg1,
    const int* __restrict__ cu2, const unsigned* __restrict__ eg2,
    const int* __restrict__ cu3, const unsigned* __restrict__ eg3,
    const int* __restrict__ ovf_n, const int4* __restrict__ ovf,
    const float* __restrict__ el, const float* __restrict__ er,
    const __half* __restrict__ f0, const __half* __restrict__ f1,
    const __half* __restrict__ f2, const __half* __restrict__ f3,
    const float* __restrict__ gat_b,
    float* __restrict__ e0, float* __restrict__ e1,
    float* __restrict__ e2, float* __restrict__ e3) {
  int grp = (blockIdx.x * 256 + threadIdx.x) >> 7;
  int lane = threadIdx.x & 63;
  int wh   = (threadIdx.x >> 6) & 1;
  int gl   = threadIdx.x >> 7;
  int g, row; const int* cu; const unsigned* eg; const __half* feat; float* out; int elo;
  if (grp < P)            { g = 0; row = grp;             cu = cu0; eg = eg0; feat = f0; out = e0; elo = 0; }
  else if (grp < 2 * P)   { g = 1; row = grp - P;         cu = cu1; eg = eg1; feat = f1; out = e1; elo = P * H; }
  else if (grp < 2*P + M) { g = 2; row = grp - 2 * P;     cu = cu2; eg = eg2; feat = f2; out = e2; elo = 2 * P * H; }
  else                    { g = 3; row = grp - 2 * P - M; cu = cu3; eg = eg3; feat = f3; out = e3; elo = (2 * P + M) * H; }
  int head = lane >> 4;
  int fo = lane << 2;
  const float* elb = el + elo;
  float erv = er[elo + row * H + head];
  int deg = cu[(size_t)row * CPAD];
  int dn = deg < CAP_G ? deg : CAP_G;
  const unsigned* ps = eg + (size_t)row * CAP_G;
  int on = ovf_n[2 + g];
  const int4* ol = ovf + (2 + g) * OVF_CAP;
  // ---- single pass: online softmax over this wave's parity edges ----
  float m = -3.4e38f, ssum = 0.f;
  float4 acc = {0.f, 0.f, 0.f, 0.f};
  int i = wh;
  for (; i + 7 <= dn; i += 8) {     // 4 edges: i, i+2, i+4, i+6
    int s0 = (int)ps[i], s1 = (int)ps[i + 2], s2 = (int)ps[i + 4], s3 = (int)ps[i + 6];
    float a = elb[s0 * H + head] + erv; a = a > 0.f ? a : 0.2f * a;
    float b = elb[s1 * H + head] + erv; b = b > 0.f ? b : 0.2f * b;
    float c = elb[s2 * H + head] + erv; c = c > 0.f ? c : 0.2f * c;
    float d = elb[s3 * H + head] + erv; d = d > 0.f ? d : 0.2f * d;
    float nm = fmaxf(m, fmaxf(fmaxf(a, b), fmaxf(c, d)));
    float sc = expf(m - nm);
    float x0 = expf(a - nm), x1 = expf(b - nm), x2 = expf(c - nm), x3 = expf(d - nm);
    float4 q0 = h4_to_f4(feat + (size_t)s0 * F + fo);
    float4 q1 = h4_to_f4(feat + (size_t)s1 * F + fo);
    float4 q2 = h4_to_f4(feat + (size_t)s2 * F + fo);
    float4 q3 = h4_to_f4(feat + (size_t)s3 * F + fo);
    ssum = ssum * sc + (x0 + x1) + (x2 + x3);
    acc.x = acc.x * sc + x0 * q0.x + x1 * q1.x + x2 * q2.x + x3 * q3.x;
    acc.y = acc.y * sc + x0 * q0.y + x1 * q1.y + x2 * q2.y + x3 * q3.y;
    acc.z = acc.z * sc + x0 * q0.z + x1 * q1.z + x2 * q2.z + x3 * q3.z;
    acc.w = acc.w * sc + x0 * q0.w + x1 * q1.w + x2 * q2.w + x3 * q3.w;
    m = nm;
  }
  for (; i + 3 <= dn; i += 4) {     // 2 edges
    int s0 = (int)ps[i], s1 = (int)ps[i + 2];
    float a = elb[s0 * H + head] + erv; a = a > 0.f ? a : 0.2f * a;
    float b = elb[s1 * H + head] + erv; b = b > 0.f ? b : 0.2f * b;
    float nm = fmaxf(m, fmaxf(a, b));
    float sc = expf(m - nm);
    float x0 = expf(a - nm), x1 = expf(b - nm);
    float4 q0 = h4_to_f4(feat + (size_t)s0 * F + fo);
    float4 q1 = h4_to_f4(feat + (size_t)s1 * F + fo);
    ssum = ssum * sc + x0 + x1;
    acc.x = acc.x * sc + x0 * q0.x + x1 * q1.x;
    acc.y = acc.y * sc + x0 * q0.y + x1 * q1.y;
    acc.z = acc.z * sc + x0 * q0.z + x1 * q1.z;
    acc.w = acc.w * sc + x0 * q0.w + x1 * q1.w;
    m = nm;
  }
  for (; i < dn; i += 2) {          // 1 edge
    int s0 = (int)ps[i];
    float a = elb[s0 * H + head] + erv; a = a > 0.f ? a : 0.2f * a;
    float nm = fmaxf(m, a);
    float sc = expf(m - nm);
    float x0 = expf(a - nm);
    float4 q0 = h4_to_f4(feat + (size_t)s0 * F + fo);
    ssum = ssum * sc + x0;
    acc.x = acc.x * sc + x0 * q0.x;
    acc.y = acc.y * sc + x0 * q0.y;
    acc.z = acc.z * sc + x0 * q0.z;
    acc.w = acc.w * sc + x0 * q0.w;
    m = nm;
  }
  // ---- cross-wave (m, ssum, acc) merge via LDS ----
  __shared__ float  pm[2][64];
  __shared__ float  pss[2][64];
  __shared__ float4 pacc[2][64];
  if (wh == 1) { pm[gl][lane] = m; pss[gl][lane] = ssum; pacc[gl][lane] = acc; }
  __syncthreads();
  if (wh == 1) return;
  {
    float m1 = pm[gl][lane], s1 = pss[gl][lane];
    float4 a1 = pacc[gl][lane];
    float nm = fmaxf(m, m1);
    float c0 = expf(m - nm), c1 = expf(m1 - nm);
    ssum = ssum * c0 + s1 * c1;
    acc.x = acc.x * c0 + a1.x * c1;
    acc.y = acc.y * c0 + a1.y * c1;
    acc.z = acc.z * c0 + a1.z * c1;
    acc.w = acc.w * c0 + a1.w * c1;
    m = nm;
  }
  // ---- overflow edges (normally zero), online update ----
  if (on > 0) {
    for (int k = 0; k < on; ++k) {
      int4 e = ol[k];
      if (e.x == row) {
        float a = elb[e.y * H + head] + erv; a = a > 0.f ? a : 0.2f * a;
        float nm = fmaxf(m, a);
        float sc = expf(m - nm);
        float x0 = expf(a - nm);
        float4 q0 = h4_to_f4(feat + (size_t)e.y * F + fo);
        ssum = ssum * sc + x0;
        acc.x = acc.x * sc + x0 * q0.x;
        acc.y = acc.y * sc + x0 * q0.y;
        acc.z = acc.z * sc + x0 * q0.z;
        acc.w = acc.w * sc + x0 * q0.w;
        m = nm;
      }
    }
  }
  float inv = 1.f / (ssum + 1e-9f);
  const float* bb = gat_b + g * F + fo;
  float4 v = {acc.x * inv + bb[0], acc.y * inv + bb[1],
              acc.z * inv + bb[2], acc.w * inv + bb[3]};
  v.x = v.x > 0.f ? v.x : expm1f(v.x);
  v.y = v.y > 0.f ? v.y : expm1f(v.y);
  v.z = v.z > 0.f ? v.z : expm1f(v.z);
  v.w = v.w > 0.f ? v.w : expm1f(v.w);
  *(float4*)(out + (size_t)row * F + fo) = v;
}

// ---------------------------------------------------------------------------
// Semantic attention weights. SR=4 (proven: W1 amortized over 4 rows, 4 ILP
// chains per load).
// ---------------------------------------------------------------------------
constexpr int SR  = 4;
constexpr int SB0 = (P + SR - 1) / SR;   // 500
constexpr int SB2 = (M + SR - 1) / SR;   // 38
constexpr int SEM_BLOCKS = 2 * SB0 + 2 * SB2;

__global__ __launch_bounds__(128) void k_sem_w_all(
    const float* __restrict__ e0, const float* __restrict__ e1,
    const float* __restrict__ e2, const float* __restrict__ e3,
    const float* __restrict__ W1, const float* __restrict__ b1,
    const float* __restrict__ W2, float* __restrict__ w) {
  int b = blockIdx.x;
  int zid, rb, n; const float* z;
  if (b < SB0)            { zid = 0; rb = b;             n = P; z = e0; }
  else if (b < 2 * SB0)   { zid = 1; rb = b - SB0;       n = P; z = e1; }
  else if (b < 2*SB0+SB2) { zid = 2; rb = b - 2 * SB0;   n = M; z = e2; }
  else                    { zid = 3; rb = b - 2*SB0-SB2; n = M; z = e3; }
  __shared__ float zs[SR][F];
  int t = threadIdx.x;
  int r0 = rb * SR;
  for (int q = t; q < SR * 64; q += 128) {
    int r = q >> 6, ln = q & 63;
    int row = r0 + r;
    float4 v = {0.f, 0.f, 0.f, 0.f};
    if (row < n) v = *(const float4*)(z + (size_t)row * F + (ln << 2));
    *(float4*)&zs[r][ln << 2] = v;
  }
  __syncthreads();
  float hid[SR];
#pragma unroll
  for (int r = 0; r < SR; ++r) hid[r] = b1[t];
  for (int k = 0; k < F; k += 4) {
    float w0 = W1[(size_t)k * SA_HID + t],       w1 = W1[(size_t)(k + 1) * SA_HID + t],
          w2 = W1[(size_t)(k + 2) * SA_HID + t], w3 = W1[(size_t)(k + 3) * SA_HID + t];
#pragma unroll
    for (int r = 0; r < SR; ++r) {
      float4 z4 = *(const float4*)&zs[r][k];
      hid[r] += z4.x * w0 + z4.y * w1 + z4.z * w2 + z4.w * w3;
    }
  }
  float w2v = W2[t];
  float local = 0.f;
  for (int r = 0; r < SR; ++r) {
    int row = r0 + r;
    if (row < n) local += tanhf(hid[r]) * w2v;
  }
  for (int o = 32; o > 0; o >>= 1) local += __shfl_down(local, o, 64);
  __shared__ float pp[2];
  if ((t & 63) == 0) pp[t >> 6] = local;
  __syncthreads();
  if (t == 0) atomicAdd(&w[zid], pp[0] + pp[1]);
}

// ---------------------------------------------------------------------------
// Final (R5 form, proven): FIN_R=4 -> 500 blocks (2/CU); patient loads issued
// first; med loop unrolled x2; cvec fused into the simi GEMM f-loop.
// ---------------------------------------------------------------------------
constexpr int FIN_R = 4;   // P % FIN_R == 0 -> 500 blocks
__global__ __launch_bounds__(256) void k_final_all(
    const float* __restrict__ e0, const float* __restrict__ e1,
    const float* __restrict__ e2, const float* __restrict__ e3,
    const float* __restrict__ w, const float* __restrict__ outW,
    const float* __restrict__ outb,
    float* __restrict__ out_med, float* __restrict__ out_pat,
    float* __restrict__ simi) {
  int t = threadIdx.x;
  // betas
  float mm0 = w[2] * (1.f / M), mm1 = w[3] * (1.f / M);
  float mmx = fmaxf(mm0, mm1);
  float bm0 = expf(mm0 - mmx), bm1 = expf(mm1 - mmx);
  float msc = 1.f / (bm0 + bm1);
  bm0 *= msc; bm1 *= msc;
  float pm0 = w[0] * (1.f / P), pm1 = w[1] * (1.f / P);
  float pmx = fmaxf(pm0, pm1);
  float bp0 = expf(pm0 - pmx), bp1 = expf(pm1 - pmx);
  float psc = 1.f / (bp0 + bp1);
  bp0 *= psc; bp1 *= psc;
  // ---- patient rows: issue loads FIRST (FIN_R*64 == 256 -> one per thread) --
  int r0 = blockIdx.x * FIN_R;
  int pr = t >> 6, pln = t & 63;
  size_t poff = (size_t)(r0 + pr) * F + (pln << 2);
  float4 pu0 = *(const float4*)(e0 + poff);
  float4 pu1 = *(const float4*)(e1 + poff);
  // ---- med combine + relu col-sum, unrolled x2 (4 loads in flight) ----
  constexpr int MED4 = M * F / 4;   // 9600
  float4 rs = {0.f, 0.f, 0.f, 0.f};
  bool wr_med = (blockIdx.x == 0);
  for (int j = t; j < MED4; j += 512) {
    float4 u0 = ((const float4*)e2)[j], u1 = ((const float4*)e3)[j];
    float4 v0, v1;
    bool second = (j + 256) < MED4;
    if (second) { v0 = ((const float4*)e2)[j + 256]; v1 = ((const float4*)e3)[j + 256]; }
    float4 r = {bm0 * u0.x + bm1 * u1.x, bm0 * u0.y + bm1 * u1.y,
                bm0 * u0.z + bm1 * u1.z, bm0 * u0.w + bm1 * u1.w};
    if (wr_med) ((float4*)out_med)[j] = r;
    rs.x += r.x > 0.f ? r.x : 0.f;
    rs.y += r.y > 0.f ? r.y : 0.f;
    rs.z += r.z > 0.f ? r.z : 0.f;
    rs.w += r.w > 0.f ? r.w : 0.f;
    if (second) {
      float4 r2 = {bm0 * v0.x + bm1 * v1.x, bm0 * v0.y + bm1 * v1.y,
                   bm0 * v0.z + bm1 * v1.z, bm0 * v0.w + bm1 * v1.w};
      if (wr_med) ((float4*)out_med)[j + 256] = r2;
      rs.x += r2.x > 0.f ? r2.x : 0.f;
      rs.y += r2.y > 0.f ? r2.y : 0.f;
      rs.z += r2.z > 0.f ? r2.z : 0.f;
      rs.w += r2.w > 0.f ? r2.w : 0.f;
    }
  }
  // ---- patient combine written to LDS + out_pat (before sv barriers) ----
  __shared__ float psh[FIN_R][F];
  {
    float4 v = {bp0 * pu0.x + bp1 * pu1.x, bp0 * pu0.y + bp1 * pu1.y,
                bp0 * pu0.z + bp1 * pu1.z, bp0 * pu0.w + bp1 * pu1.w};
    *(float4*)(out_pat + poff) = v;
    v.x = v.x > 0.f ? v.x : 0.f; v.y = v.y > 0.f ? v.y : 0.f;
    v.z = v.z > 0.f ? v.z : 0.f; v.w = v.w > 0.f ? v.w : 0.f;
    *(float4*)&psh[pr][pln << 2] = v;
  }
  // ---- sv reduce (barriers also publish psh) ----
  __shared__ float4 sv4[4][64];
  sv4[t >> 6][t & 63] = rs;
  __syncthreads();
  __shared__ float sv[F];
  if (t < 64) {
    float4 a = sv4[0][t], b = sv4[1][t], c = sv4[2][t], d = sv4[3][t];
    sv[t * 4 + 0] = a.x + b.x + c.x + d.x;
    sv[t * 4 + 1] = a.y + b.y + c.y + d.y;
    sv[t * 4 + 2] = a.z + b.z + c.z + d.z;
    sv[t * 4 + 3] = a.w + b.w + c.w + d.w;
  }
  __syncthreads();
  // ---- fused cvec + simi GEMM: 8 outW loads, 5 acc chains per f-step ----
  if (t < M) {
    float acc[FIN_R];
#pragma unroll
    for (int r = 0; r < FIN_R; ++r) acc[r] = 0.f;
    float cv = (float)M * outb[t];
    for (int f = 0; f < F; f += 4) {
      float w0 = outW[(size_t)f * M + t],       w1 = outW[(size_t)(f + 1) * M + t],
            w2 = outW[(size_t)(f + 2) * M + t], w3 = outW[(size_t)(f + 3) * M + t];
      float b0 = outW[(size_t)(F + f) * M + t],     b1 = outW[(size_t)(F + f + 1) * M + t],
            b2 = outW[(size_t)(F + f + 2) * M + t], b3 = outW[(size_t)(F + f + 3) * M + t];
      cv += sv[f] * b0 + sv[f + 1] * b1 + sv[f + 2] * b2 + sv[f + 3] * b3;
#pragma unroll
      for (int r = 0; r < FIN_R; ++r) {
        float4 p4 = *(const float4*)&psh[r][f];
        acc[r] += p4.x * w0 + p4.y * w1 + p4.z * w2 + p4.w * w3;
      }
    }
#pragma unroll
    for (int r = 0; r < FIN_R; ++r)
      simi[(size_t)(r0 + r) * M + t] = (float)M * acc[r] + cv;
  }
}

// ---------------------------------------------------------------------------
extern "C" void kernel_launch(void* const* d_in, const int* in_sizes, int n_in,
                              void* d_out, int out_size, void* d_ws, size_t ws_size,
                              hipStream_t stream) {
  const int*   adj1_rows = (const int*)d_in[0];
  const int*   adj1_cols = (const int*)d_in[1];
  const float* adj1_vals = (const float*)d_in[2];
  const int*   adj2_rows = (const int*)d_in[3];
  const int*   adj2_cols = (const int*)d_in[4];
  const float* adj2_vals = (const float*)d_in[5];
  const int*   g0_src = (const int*)d_in[6];
  const int*   g0_dst = (const int*)d_in[7];
  const int*   g1_src = (const int*)d_in[8];
  const int*   g1_dst = (const int*)d_in[9];
  const int*   g2_src = (const int*)d_in[10];
  const int*   g2_dst = (const int*)d_in[11];
  const int*   g3_src = (const int*)d_in[12];
  const int*   g3_dst = (const int*)d_in[13];
  // d_in[14] = keepRate (unused, == 1)
  const float* pE     = (const float*)d_in[15];
  const float* mE     = (const float*)d_in[16];
  const float* dE     = (const float*)d_in[17];
  const float* gat_W  = (const float*)d_in[18];
  const float* gat_al = (const float*)d_in[19];
  const float* gat_ar = (const float*)d_in[20];
  const float* gat_b  = (const float*)d_in[21];
  const float* sa_W1  = (const float*)d_in[22];
  const float* sa_b1  = (const float*)d_in[23];
  const float* sa_W2  = (const float*)d_in[24];
  const float* out_W  = (const float*)d_in[25];
  const float* out_b  = (const float*)d_in[26];

  // ---- workspace layout: [zeroed (padded counters) | ELL | fp16 | fp32] ----
  int* ip = (int*)d_ws;
  int* cur1 = ip; ip += (size_t)N1 * CPAD;
  int* cur2 = ip; ip += (size_t)N2 * CPAD;
  int* cu0  = ip; ip += (size_t)P * CPAD;
  int* cu1  = ip; ip += (size_t)P * CPAD;
  int* cu2  = ip; ip += (size_t)M * CPAD;
  int* cu3  = ip; ip += (size_t)M * CPAD;
  int* ovf_n = ip; ip += 6;
  float* wbuf = (float*)ip; ip += 4;
  size_t memset_bytes = (size_t)((char*)ip - (char*)d_ws);

  uintptr_t up = ((uintptr_t)ip + 15) & ~(uintptr_t)15;
  int4* ovf = (int4*)up;                       // 6 * OVF_CAP
  uint2* ell1 = (uint2*)(ovf + 6 * OVF_CAP);   // N1 * CAP_A
  uint2* ell2 = ell1 + (size_t)N1 * CAP_A;     // N2 * CAP_A
  unsigned* eg0 = (unsigned*)(ell2 + (size_t)N2 * CAP_A);
  unsigned* eg1 = eg0 + (size_t)P * CAP_G;
  unsigned* eg2 = eg1 + (size_t)P * CAP_G;
  unsigned* eg3 = eg2 + (size_t)M * CAP_G;
  // fp16 region (16B-aligned by construction)
  __half* hp = (__half*)(eg3 + (size_t)M * CAP_G);
  __half* pEh   = hp; hp += (size_t)P * F;
  __half* mEh   = hp; hp += (size_t)M * F;
  __half* dEh   = hp; hp += (size_t)DG * F;
  __half* lat1h = hp; hp += (size_t)N1 * F;
  __half* lat2h = hp; hp += (size_t)N2 * F;
  __half* f0h   = hp; hp += (size_t)P * F;
  __half* f1h   = hp; hp += (size_t)P * F;
  __half* f2h   = hp; hp += (size_t)M * F;
  __half* f3h   = hp; hp += (size_t)M * F;
  float* fp = (float*)hp;
  float* lat1f = fp; fp += (size_t)N1 * F;
  float* lat2f = fp; fp += (size_t)N2 * F;
  float* acc1  = fp; fp += (size_t)N1 * F;
  float* acc2  = fp; fp += (size_t)N2 * F;
  float* el    = fp; fp += (size_t)(2 * P + 2 * M) * H;
  float* er    = fp; fp += (size_t)(2 * P + 2 * M) * H;
  float* e0b   = fp; fp += (size_t)P * F;
  float* e1b   = fp; fp += (size_t)P * F;
  float* e2b   = fp; fp += (size_t)M * F;
  float* e3b   = fp; fp += (size_t)M * F;

  // ---- output layout: (simi_pm, d_gcn, med, m_gcn, patient) ----
  float* out_simi = (float*)d_out;               // P*M
  float* out_dgcn = out_simi + (size_t)P * M;    // DG*F
  float* out_med  = out_dgcn + (size_t)DG * F;   // M*F
  float* out_mgcn = out_med  + (size_t)M * F;    // M*F
  float* out_pat  = out_mgcn + (size_t)M * F;    // P*F

  // ---- zero padded counters (~540 KB) ----
  hipMemsetAsync(d_ws, 0, memset_bytes, stream);

  // ---- ELL build + fused fp16 embed cast: ONE dispatch ----
  int eb = ((HOE + 3) / 4 + 255) / 256;
  k_build<<<eb, 256, 0, stream>>>(adj1_rows, adj1_cols, adj1_vals,
                                  adj2_rows, adj2_cols, adj2_vals,
                                  g0_dst, g0_src, g1_dst, g1_src,
                                  g2_dst, g2_src, g3_dst, g3_src,
                                  cur1, ell1, cur2, ell2,
                                  cu0, eg0, cu1, eg1, cu2, eg2, cu3, eg3,
                                  ovf_n, ovf,
                                  pE, mE, dE, pEh, mEh, dEh);

  // ---- GNN: 2 layers, 2 waves per row (edge-parity split) ----
  int sb = (N1 + N2) / 2;
  k_spmm<1><<<sb, 256, 0, stream>>>(cur1, ell1, cur2, ell2, ovf_n, ovf,
                                    pEh, mEh, dEh, lat1f, lat2f, lat1h, lat2h,
                                    acc1, acc2, out_mgcn, out_dgcn);
  k_spmm<2><<<sb, 256, 0, stream>>>(cur1, ell1, cur2, ell2, ovf_n, ovf,
                                    pEh, mEh, dEh, lat1f, lat2f, lat1h, lat2h,
                                    acc1, acc2, out_mgcn, out_dgcn);

  // ---- 4 GATs: scalar feature GEMM + 2-wave-split aggregation ----
  k_gat_feat_all<<<FEAT_BLOCKS, 256, 0, stream>>>(acc1, acc2, gat_W, gat_al, gat_ar,
                                                  f0h, f1h, f2h, f3h, el, er);
  int ab = (2 * P + 2 * M) / 2;   // 4300 groups * 128 threads / 256
  k_gat_agg_all<<<ab, 256, 0, stream>>>(cu0, eg0, cu1, eg1, cu2, eg2, cu3, eg3,
                                        ovf_n, ovf, el, er, f0h, f1h, f2h, f3h, gat_b,
                                        e0b, e1b, e2b, e3b);

  // ---- semantic attention weights ----
  k_sem_w_all<<<SEM_BLOCKS, 128, 0, stream>>>(e0b, e1b, e2b, e3b, sa_W1, sa_b1, sa_W2, wbuf);

  // ---- final: med+cvec+patient+simi fused (FIN_R=4, 500 blocks) ----
  k_final_all<<<P / FIN_R, 256, 0, stream>>>(e0b, e1b, e2b, e3b, wbuf, out_W, out_b,
                                             out_med, out_pat, out_simi);
}

// Round 8
// 304.443 us; speedup vs baseline: 1.1170x; 1.1170x over previous
//
#include <hip/hip_runtime.h>
#include <hip/hip_fp16.h>
#include <cmath>
#include <cstdint>

// Problem constants (fixed by the reference).
constexpr int P  = 2000, M = 150, DG = 2000, F = 256, H = 4, DH = 64;
constexpr int N1 = P + M;          // 2150
constexpr int N2 = P + DG;         // 4000
constexpr int E1 = 137600, E2 = 256000, EGP = 64000, EGM = 4800;
constexpr int SA_HID = 128;

// Edge-range offsets for the fused build kernel.
constexpr int HO1 = E1, HO2 = E1 + E2, HO3 = HO2 + EGP, HO4 = HO3 + EGP,
              HO5 = HO4 + EGM, HOE = HO5 + EGM;   // 531200 total edges

// ELL capacities (overflow list guarantees correctness regardless).
constexpr int CAP_A = 160;
constexpr int CAP_G = 96;
constexpr int OVF_CAP = 4096;

// One counter per 64B line (R7: removed same-line atomic serialization).
constexpr int CPAD = 16;

// ---- fp16 helpers -----------------------------------------------------------
__device__ __forceinline__ float4 h4_to_f4(const __half* p) {
  union { ushort4 u4; __half2 h2[2]; } u;
  u.u4 = *(const ushort4*)p;
  float2 lo = __half22float2(u.h2[0]);
  float2 hi = __half22float2(u.h2[1]);
  return make_float4(lo.x, lo.y, hi.x, hi.y);
}
__device__ __forceinline__ void f4_to_h4(__half* p, float4 v) {
  union { ushort4 u4; __half2 h2[2]; } u;
  u.h2[0] = __float22half2_rn(make_float2(v.x, v.y));
  u.h2[1] = __float22half2_rn(make_float2(v.z, v.w));
  *(ushort4*)p = u.u4;
}

// ---------------------------------------------------------------------------
// ELL build (padded counters) + fused fp32->fp16 embed cast.
// ---------------------------------------------------------------------------
constexpr int CAST_CH = (P * F + M * F + DG * F) / 8;   // 8-float chunks

__global__ __launch_bounds__(256) void k_build(
    const int* __restrict__ a1r, const int* __restrict__ a1c, const float* __restrict__ a1v,
    const int* __restrict__ a2r, const int* __restrict__ a2c, const float* __restrict__ a2v,
    const int* __restrict__ d0, const int* __restrict__ s0,
    const int* __restrict__ d1, const int* __restrict__ s1,
    const int* __restrict__ d2, const int* __restrict__ s2,
    const int* __restrict__ d3, const int* __restrict__ s3,
    int* cur1, uint2* ell1, int* cur2, uint2* ell2,
    int* cu0, unsigned* eg0, int* cu1, unsigned* eg1,
    int* cu2, unsigned* eg2, int* cu3, unsigned* eg3,
    int* __restrict__ ovf_n, int4* __restrict__ ovf,
    const float* __restrict__ pEf, const float* __restrict__ mEf,
    const float* __restrict__ dEf,
    __half* __restrict__ pEh, __half* __restrict__ mEh, __half* __restrict__ dEh) {
  int tid = blockIdx.x * 256 + threadIdx.x;
  int T = gridDim.x * 256;
  int seg[4], row[4]; unsigned p0[4], p1[4];
#pragma unroll
  for (int u = 0; u < 4; ++u) {
    int i = tid + u * T;
    seg[u] = -1;
    if (i < HOE) {
      if (i < HO1)      { seg[u] = 0; row[u] = a1r[i]; p0[u] = (unsigned)a1c[i]; p1[u] = __float_as_uint(a1v[i]); }
      else if (i < HO2) { int j = i - HO1; seg[u] = 1; row[u] = a2r[j]; p0[u] = (unsigned)a2c[j]; p1[u] = __float_as_uint(a2v[j]); }
      else if (i < HO3) { int j = i - HO2; seg[u] = 2; row[u] = d0[j]; p0[u] = (unsigned)s0[j]; }
      else if (i < HO4) { int j = i - HO3; seg[u] = 3; row[u] = d1[j]; p0[u] = (unsigned)s1[j]; }
      else if (i < HO5) { int j = i - HO4; seg[u] = 4; row[u] = d2[j]; p0[u] = (unsigned)s2[j]; }
      else              { int j = i - HO5; seg[u] = 5; row[u] = d3[j]; p0[u] = (unsigned)s3[j]; }
    }
  }
#pragma unroll
  for (int u = 0; u < 4; ++u) {
    int r = row[u];
    switch (seg[u]) {
      case 0: { int slot = atomicAdd(&cur1[(size_t)r * CPAD], 1);
        if (slot < CAP_A) ell1[(size_t)r * CAP_A + slot] = make_uint2(p0[u], p1[u]);
        else { int o = atomicAdd(&ovf_n[0], 1); if (o < OVF_CAP) ovf[0 * OVF_CAP + o] = make_int4(r, (int)p0[u], (int)p1[u], 0); } } break;
      case 1: { int slot = atomicAdd(&cur2[(size_t)r * CPAD], 1);
        if (slot < CAP_A) ell2[(size_t)r * CAP_A + slot] = make_uint2(p0[u], p1[u]);
        else { int o = atomicAdd(&ovf_n[1], 1); if (o < OVF_CAP) ovf[1 * OVF_CAP + o] = make_int4(r, (int)p0[u], (int)p1[u], 0); } } break;
      case 2: { int slot = atomicAdd(&cu0[(size_t)r * CPAD], 1);
        if (slot < CAP_G) eg0[(size_t)r * CAP_G + slot] = p0[u];
        else { int o = atomicAdd(&ovf_n[2], 1); if (o < OVF_CAP) ovf[2 * OVF_CAP + o] = make_int4(r, (int)p0[u], 0, 0); } } break;
      case 3: { int slot = atomicAdd(&cu1[(size_t)r * CPAD], 1);
        if (slot < CAP_G) eg1[(size_t)r * CAP_G + slot] = p0[u];
        else { int o = atomicAdd(&ovf_n[3], 1); if (o < OVF_CAP) ovf[3 * OVF_CAP + o] = make_int4(r, (int)p0[u], 0, 0); } } break;
      case 4: { int slot = atomicAdd(&cu2[(size_t)r * CPAD], 1);
        if (slot < CAP_G) eg2[(size_t)r * CAP_G + slot] = p0[u];
        else { int o = atomicAdd(&ovf_n[4], 1); if (o < OVF_CAP) ovf[4 * OVF_CAP + o] = make_int4(r, (int)p0[u], 0, 0); } } break;
      case 5: { int slot = atomicAdd(&cu3[(size_t)r * CPAD], 1);
        if (slot < CAP_G) eg3[(size_t)r * CAP_G + slot] = p0[u];
        else { int o = atomicAdd(&ovf_n[5], 1); if (o < OVF_CAP) ovf[5 * OVF_CAP + o] = make_int4(r, (int)p0[u], 0, 0); } } break;
      default: break;
    }
  }
  // Fused embed cast fp32 -> fp16 (independent streaming work).
  for (int c = tid; c < CAST_CH; c += T) {
    int j = c * 8;
    const float* src; __half* dst;
    if (j < P * F)              { src = pEf + j;               dst = pEh + j; }
    else if (j < P * F + M * F) { src = mEf + (j - P * F);     dst = mEh + (j - P * F); }
    else                        { src = dEf + (j - P*F - M*F); dst = dEh + (j - P*F - M*F); }
    float4 a = *(const float4*)src, b = *(const float4*)(src + 4);
    f4_to_h4(dst, a);
    f4_to_h4(dst + 4, b);
  }
}

// ---------------------------------------------------------------------------
// SPMM: TWO waves per row (edges split by parity, LDS combine), fp16 gathers,
// fp32 accumulate (R5 form, proven 304.6us; R6 half-wave split REVERTED:
// +14us/dispatch from LDS bank conflicts).
// R8: XCD-aware bijective block swizzle — contiguous row chunk per XCD so the
// per-XCD L2 working set (ELL chunk ~1MB + fp16 tables ~3MB) fits in 4MB.
// Measured R7: 10.4MB HBM fetch/dispatch = full ELL re-fetch (XCD thrash).
// ---------------------------------------------------------------------------
constexpr int SPMM_NBLK = (N1 + N2) / 2;   // 3075
template<int LAYER>
__global__ __launch_bounds__(256) void k_spmm(
    const int* __restrict__ cur1, const uint2* __restrict__ ell1,
    const int* __restrict__ cur2, const uint2* __restrict__ ell2,
    const int* __restrict__ ovf_n, const int4* __restrict__ ovf,
    const __half* __restrict__ pEh, const __half* __restrict__ mEh,
    const __half* __restrict__ dEh,
    float* __restrict__ lat1f, float* __restrict__ lat2f,
    __half* __restrict__ lat1h, __half* __restrict__ lat2h,
    float* __restrict__ acc1, float* __restrict__ acc2,
    float* __restrict__ out_mgcn, float* __restrict__ out_dgcn) {
  // Bijective XCD swizzle (nb=3075, nb%8=3): XCD k gets a contiguous chunk.
  constexpr int Q = SPMM_NBLK / 8, Rr = SPMM_NBLK % 8;
  int xcd = blockIdx.x & 7, idx = blockIdx.x >> 3;
  int swz = (xcd < Rr) ? xcd * (Q + 1) + idx : Rr * (Q + 1) + (xcd - Rr) * Q + idx;
  int grp = swz * 2 + (threadIdx.x >> 7);            // row-group id
  int lane = threadIdx.x & 63;
  int wh   = (threadIdx.x >> 6) & 1;                 // wave-half within group
  int gl   = threadIdx.x >> 7;                       // group slot in block (0/1)
  bool g2 = grp >= N1;
  int row = g2 ? grp - N1 : grp;
  const uint2* pe = (g2 ? ell2 : ell1) + (size_t)row * CAP_A;
  const __half* latinh = g2 ? lat2h : lat1h;
  const __half* tailEh = g2 ? dEh : mEh;
  int deg = (g2 ? cur2 : cur1)[(size_t)row * CPAD];
  int dn = deg < CAP_A ? deg : CAP_A;
  int fo = lane << 2;
  float4 s = {0.f, 0.f, 0.f, 0.f};
  auto fetch = [&](int c) -> float4 {
    const __half* b;
    if (LAYER == 1) b = (c < P) ? (pEh + (size_t)c * F) : (tailEh + (size_t)(c - P) * F);
    else            b = latinh + (size_t)c * F;
    return h4_to_f4(b + fo);
  };
  int i = wh;
  for (; i + 15 <= dn; i += 16) {    // 8 edges: i, i+2, ..., i+14
    uint2 m[8]; float4 a[8];
#pragma unroll
    for (int u = 0; u < 8; ++u) m[u] = pe[i + 2 * u];
#pragma unroll
    for (int u = 0; u < 8; ++u) a[u] = fetch((int)m[u].x);
#pragma unroll
    for (int u = 0; u < 8; ++u) {
      float v = __uint_as_float(m[u].y);
      s.x += v * a[u].x; s.y += v * a[u].y; s.z += v * a[u].z; s.w += v * a[u].w;
    }
  }
  for (; i < dn; i += 2) {
    uint2 m = pe[i];
    float v = __uint_as_float(m.y);
    float4 a = fetch((int)m.x);
    s.x += v * a.x; s.y += v * a.y; s.z += v * a.z; s.w += v * a.w;
  }
  __shared__ float part[2][F];
  if (wh == 1) *(float4*)&part[gl][fo] = s;
  __syncthreads();
  if (wh == 1) return;
  {
    float4 p = *(const float4*)&part[gl][fo];
    s.x += p.x; s.y += p.y; s.z += p.z; s.w += p.w;
  }
  // Overflow edges (normally zero), wave 0 only.
  {
    int gi = g2 ? 1 : 0;
    int on = ovf_n[gi];
    if (on > 0) {
      const int4* ol = ovf + gi * OVF_CAP;
      for (int k = 0; k < on; ++k) {
        int4 e = ol[k];
        if (e.x == row) {
          float v = __int_as_float(e.z);
          float4 a = fetch(e.y);
          s.x += v * a.x; s.y += v * a.y; s.z += v * a.z; s.w += v * a.w;
        }
      }
    }
  }
  float4 l;
  l.x = s.x > 0.f ? s.x : 0.5f * s.x;
  l.y = s.y > 0.f ? s.y : 0.5f * s.y;
  l.z = s.z > 0.f ? s.z : 0.5f * s.z;
  l.w = s.w > 0.f ? s.w : 0.5f * s.w;
  if (LAYER == 1) {
    *(float4*)((g2 ? lat2f : lat1f) + (size_t)row * F + fo) = l;   // exact own-row
    f4_to_h4((g2 ? lat2h : lat1h) + (size_t)row * F + fo, l);      // gather copy
  } else {
    const float* latf = g2 ? lat2f : lat1f;
    float4 b = *(const float4*)(latf + (size_t)row * F + fo);
    float4 a = {b.x + l.x, b.y + l.y, b.z + l.z, b.w + l.w};
    *(float4*)((g2 ? acc2 : acc1) + (size_t)row * F + fo) = a;
    if (row >= P)
      *(float4*)((g2 ? out_dgcn : out_mgcn) + (size_t)(row - P) * F + fo) = a;
  }
}

// ---------------------------------------------------------------------------
// All 4 GAT feature GEMMs. FR=8 (R8/R9: occupancy beats W-traffic reduction).
// ---------------------------------------------------------------------------
constexpr int FR  = 8;
constexpr int NB0 = (P + FR - 1) / FR;   // 250
constexpr int NB2 = (M + FR - 1) / FR;   // 19
constexpr int FEAT_BLOCKS = 2 * NB0 + 2 * NB2;

__global__ __launch_bounds__(256) void k_gat_feat_all(
    const float* __restrict__ acc1, const float* __restrict__ acc2,
    const float* __restrict__ gat_W, const float* __restrict__ gat_al,
    const float* __restrict__ gat_ar,
    __half* __restrict__ f0, __half* __restrict__ f1,
    __half* __restrict__ f2, __half* __restrict__ f3,
    float* __restrict__ el, float* __restrict__ er) {
  int b = blockIdx.x;
  int g, rb, n; const float* h; __half* fout;
  if (b < NB0)            { g = 0; rb = b;              n = P; h = acc1; fout = f0; }
  else if (b < 2 * NB0)   { g = 1; rb = b - NB0;        n = P; h = acc2; fout = f1; }
  else if (b < 2*NB0+NB2) { g = 2; rb = b - 2 * NB0;    n = M; h = acc1 + (size_t)P * F; fout = f2; }
  else                    { g = 3; rb = b - 2*NB0 - NB2; n = M; h = acc1 + (size_t)P * F; fout = f3; }
  int elo = (g == 0) ? 0 : (g == 1) ? P * H : (g == 2) ? 2 * P * H : (2 * P + M) * H;
  const float* W = gat_W + (size_t)g * F * F;
  __shared__ float hs[FR][F];
  int t = threadIdx.x;
  int r0 = rb * FR;
  for (int q = t; q < FR * 64; q += 256) {
    int r = q >> 6, ln = q & 63;
    int row = r0 + r;
    float4 v = {0.f, 0.f, 0.f, 0.f};
    if (row < n) v = *(const float4*)(h + (size_t)row * F + (ln << 2));
    *(float4*)&hs[r][ln << 2] = v;
  }
  __syncthreads();
  float acc[FR];
#pragma unroll
  for (int r = 0; r < FR; ++r) acc[r] = 0.f;
  for (int k = 0; k < F; k += 4) {
    float w0 = W[(size_t)k * F + t],       w1 = W[(size_t)(k + 1) * F + t],
          w2 = W[(size_t)(k + 2) * F + t], w3 = W[(size_t)(k + 3) * F + t];
#pragma unroll
    for (int r = 0; r < FR; ++r) {
      float4 h4 = *(const float4*)&hs[r][k];
      acc[r] += h4.x * w0 + h4.y * w1 + h4.z * w2 + h4.w * w3;
    }
  }
  int head = t >> 6, d = t & 63;           // one wave == one head
  float av = gat_al[g * H * DH + head * DH + d];
  float rv = gat_ar[g * H * DH + head * DH + d];
#pragma unroll
  for (int r = 0; r < FR; ++r) {
    int row = r0 + r;
    if (row < n) {
      fout[(size_t)row * F + t] = __float2half_rn(acc[r]);
      float cl = acc[r] * av, cr = acc[r] * rv;
      for (int o = 32; o > 0; o >>= 1) {
        cl += __shfl_down(cl, o, 64);
        cr += __shfl_down(cr, o, 64);
      }
      if (d == 0) { el[elo + row * H + head] = cl; er[elo + row * H + head] = cr; }
    }
  }
}

// ---------------------------------------------------------------------------
// All 4 GAT aggregations: TWO waves per dst-row (edge-parity split).
// R5 form (proven): two-pass, pass-2 unrolled to 4 edge gathers in flight.
// (R6 single-pass online softmax reverted with the R7 regression.)
// ---------------------------------------------------------------------------
__global__ __launch_bounds__(256) void k_gat_agg_all(
    const int* __restrict__ cu0, const unsigned* __restrict__ eg0,
    const int* __restrict__ cu1, const unsigned* __restrict__ eg1,
    const int* __restrict__ cu2, const unsigned* __restrict__ eg2,
    const int* __restrict__ cu3, const unsigned* __restrict__ eg3,
    const int* __restrict__ ovf_n, const int4* __restrict__ ovf,
    const float* __restrict__ el, const float* __restrict__ er,
    const __half* __restrict__ f0, const __half* __restrict__ f1,
    const __half* __restrict__ f2, const __half* __restrict__ f3,
    const float* __restrict__ gat_b,
    float* __restrict__ e0, float* __restrict__ e1,
    float* __restrict__ e2, float* __restrict__ e3) {
  int grp = (blockIdx.x * 256 + threadIdx.x) >> 7;
  int lane = threadIdx.x & 63;
  int wh   = (threadIdx.x >> 6) & 1;
  int gl   = threadIdx.x >> 7;
  int g, row; const int* cu; const unsigned* eg; const __half* feat; float* out; int elo;
  if (grp < P)            { g = 0; row = grp;             cu = cu0; eg = eg0; feat = f0; out = e0; elo = 0; }
  else if (grp < 2 * P)   { g = 1; row = grp - P;         cu = cu1; eg = eg1; feat = f1; out = e1; elo = P * H; }
  else if (grp < 2*P + M) { g = 2; row = grp - 2 * P;     cu = cu2; eg = eg2; feat = f2; out = e2; elo = 2 * P * H; }
  else                    { g = 3; row = grp - 2 * P - M; cu = cu3; eg = eg3; feat = f3; out = e3; elo = (2 * P + M) * H; }
  int head = lane >> 4;
  int fo = lane << 2;
  const float* elb = el + elo;
  float erv = er[elo + row * H + head];
  int deg = cu[(size_t)row * CPAD];
  int dn = deg < CAP_G ? deg : CAP_G;
  const unsigned* ps = eg + (size_t)row * CAP_G;
  int on = ovf_n[2 + g];
  const int4* ol = ovf + (2 + g) * OVF_CAP;
  // ---- pass 1: max over this wave's parity edges ----
  float mx = -3.4e38f;
  int i = wh;
  for (; i + 7 <= dn; i += 8) {     // 4 edges: i, i+2, i+4, i+6
    int s0 = (int)ps[i], s1 = (int)ps[i + 2], s2 = (int)ps[i + 4], s3 = (int)ps[i + 6];
    float a = elb[s0 * H + head] + erv, b = elb[s1 * H + head] + erv,
          c = elb[s2 * H + head] + erv, d = elb[s3 * H + head] + erv;
    a = a > 0.f ? a : 0.2f * a; b = b > 0.f ? b : 0.2f * b;
    c = c > 0.f ? c : 0.2f * c; d = d > 0.f ? d : 0.2f * d;
    mx = fmaxf(mx, fmaxf(fmaxf(a, b), fmaxf(c, d)));
  }
  for (; i < dn; i += 2) {
    float a = elb[(int)ps[i] * H + head] + erv;
    a = a > 0.f ? a : 0.2f * a;
    mx = fmaxf(mx, a);
  }
  if (wh == 0 && on > 0) {
    for (int k = 0; k < on; ++k) {
      int4 e = ol[k];
      if (e.x == row) {
        float a = elb[e.y * H + head] + erv;
        a = a > 0.f ? a : 0.2f * a;
        mx = fmaxf(mx, a);
      }
    }
  }
  __shared__ float mxs[2][2][64];
  mxs[gl][wh][lane] = mx;
  __syncthreads();
  mx = fmaxf(mxs[gl][0][lane], mxs[gl][1][lane]);
  // ---- pass 2: exp-sum + weighted aggregation, 4 gathers in flight ----
  float ssum = 0.f;
  float4 acc = {0.f, 0.f, 0.f, 0.f};
  i = wh;
  for (; i + 7 <= dn; i += 8) {     // 4 edges: i, i+2, i+4, i+6
    int s0 = (int)ps[i], s1 = (int)ps[i + 2], s2 = (int)ps[i + 4], s3 = (int)ps[i + 6];
    float a = elb[s0 * H + head] + erv; a = a > 0.f ? a : 0.2f * a;
    float b = elb[s1 * H + head] + erv; b = b > 0.f ? b : 0.2f * b;
    float c = elb[s2 * H + head] + erv; c = c > 0.f ? c : 0.2f * c;
    float d = elb[s3 * H + head] + erv; d = d > 0.f ? d : 0.2f * d;
    float x0 = expf(a - mx), x1 = expf(b - mx), x2 = expf(c - mx), x3 = expf(d - mx);
    float4 q0 = h4_to_f4(feat + (size_t)s0 * F + fo);
    float4 q1 = h4_to_f4(feat + (size_t)s1 * F + fo);
    float4 q2 = h4_to_f4(feat + (size_t)s2 * F + fo);
    float4 q3 = h4_to_f4(feat + (size_t)s3 * F + fo);
    ssum += (x0 + x1) + (x2 + x3);
    acc.x += x0 * q0.x + x1 * q1.x + x2 * q2.x + x3 * q3.x;
    acc.y += x0 * q0.y + x1 * q1.y + x2 * q2.y + x3 * q3.y;
    acc.z += x0 * q0.z + x1 * q1.z + x2 * q2.z + x3 * q3.z;
    acc.w += x0 * q0.w + x1 * q1.w + x2 * q2.w + x3 * q3.w;
  }
  for (; i + 3 <= dn; i += 4) {     // 2 edges
    int s0 = (int)ps[i], s1 = (int)ps[i + 2];
    float a = elb[s0 * H + head] + erv; a = a > 0.f ? a : 0.2f * a;
    float b = elb[s1 * H + head] + erv; b = b > 0.f ? b : 0.2f * b;
    float x0 = expf(a - mx), x1 = expf(b - mx);
    float4 q0 = h4_to_f4(feat + (size_t)s0 * F + fo);
    float4 q1 = h4_to_f4(feat + (size_t)s1 * F + fo);
    ssum += x0 + x1;
    acc.x += x0 * q0.x + x1 * q1.x;
    acc.y += x0 * q0.y + x1 * q1.y;
    acc.z += x0 * q0.z + x1 * q1.z;
    acc.w += x0 * q0.w + x1 * q1.w;
  }
  for (; i < dn; i += 2) {
    int s0 = (int)ps[i];
    float a = elb[s0 * H + head] + erv; a = a > 0.f ? a : 0.2f * a;
    float x0 = expf(a - mx);
    float4 q0 = h4_to_f4(feat + (size_t)s0 * F + fo);
    ssum += x0;
    acc.x += x0 * q0.x; acc.y += x0 * q0.y; acc.z += x0 * q0.z; acc.w += x0 * q0.w;
  }
  __shared__ float4 pacc[2][64];
  __shared__ float  pss[2][64];
  if (wh == 1) { pacc[gl][lane] = acc; pss[gl][lane] = ssum; }
  __syncthreads();
  if (wh == 1) return;
  {
    float4 pa = pacc[gl][lane];
    acc.x += pa.x; acc.y += pa.y; acc.z += pa.z; acc.w += pa.w;
    ssum += pss[gl][lane];
  }
  if (on > 0) {
    for (int k = 0; k < on; ++k) {
      int4 e = ol[k];
      if (e.x == row) {
        float a = elb[e.y * H + head] + erv; a = a > 0.f ? a : 0.2f * a;
        float x0 = expf(a - mx);
        float4 q0 = h4_to_f4(feat + (size_t)e.y * F + fo);
        ssum += x0;
        acc.x += x0 * q0.x; acc.y += x0 * q0.y; acc.z += x0 * q0.z; acc.w += x0 * q0.w;
      }
    }
  }
  float inv = 1.f / (ssum + 1e-9f);
  const float* bb = gat_b + g * F + fo;
  float4 v = {acc.x * inv + bb[0], acc.y * inv + bb[1],
              acc.z * inv + bb[2], acc.w * inv + bb[3]};
  v.x = v.x > 0.f ? v.x : expm1f(v.x);
  v.y = v.y > 0.f ? v.y : expm1f(v.y);
  v.z = v.z > 0.f ? v.z : expm1f(v.z);
  v.w = v.w > 0.f ? v.w : expm1f(v.w);
  *(float4*)(out + (size_t)row * F + fo) = v;
}

// ---------------------------------------------------------------------------
// Semantic attention weights. SR=4 (proven: W1 amortized over 4 rows, 4 ILP
// chains per load).
// ---------------------------------------------------------------------------
constexpr int SR  = 4;
constexpr int SB0 = (P + SR - 1) / SR;   // 500
constexpr int SB2 = (M + SR - 1) / SR;   // 38
constexpr int SEM_BLOCKS = 2 * SB0 + 2 * SB2;

__global__ __launch_bounds__(128) void k_sem_w_all(
    const float* __restrict__ e0, const float* __restrict__ e1,
    const float* __restrict__ e2, const float* __restrict__ e3,
    const float* __restrict__ W1, const float* __restrict__ b1,
    const float* __restrict__ W2, float* __restrict__ w) {
  int b = blockIdx.x;
  int zid, rb, n; const float* z;
  if (b < SB0)            { zid = 0; rb = b;             n = P; z = e0; }
  else if (b < 2 * SB0)   { zid = 1; rb = b - SB0;       n = P; z = e1; }
  else if (b < 2*SB0+SB2) { zid = 2; rb = b - 2 * SB0;   n = M; z = e2; }
  else                    { zid = 3; rb = b - 2*SB0-SB2; n = M; z = e3; }
  __shared__ float zs[SR][F];
  int t = threadIdx.x;
  int r0 = rb * SR;
  for (int q = t; q < SR * 64; q += 128) {
    int r = q >> 6, ln = q & 63;
    int row = r0 + r;
    float4 v = {0.f, 0.f, 0.f, 0.f};
    if (row < n) v = *(const float4*)(z + (size_t)row * F + (ln << 2));
    *(float4*)&zs[r][ln << 2] = v;
  }
  __syncthreads();
  float hid[SR];
#pragma unroll
  for (int r = 0; r < SR; ++r) hid[r] = b1[t];
  for (int k = 0; k < F; k += 4) {
    float w0 = W1[(size_t)k * SA_HID + t],       w1 = W1[(size_t)(k + 1) * SA_HID + t],
          w2 = W1[(size_t)(k + 2) * SA_HID + t], w3 = W1[(size_t)(k + 3) * SA_HID + t];
#pragma unroll
    for (int r = 0; r < SR; ++r) {
      float4 z4 = *(const float4*)&zs[r][k];
      hid[r] += z4.x * w0 + z4.y * w1 + z4.z * w2 + z4.w * w3;
    }
  }
  float w2v = W2[t];
  float local = 0.f;
  for (int r = 0; r < SR; ++r) {
    int row = r0 + r;
    if (row < n) local += tanhf(hid[r]) * w2v;
  }
  for (int o = 32; o > 0; o >>= 1) local += __shfl_down(local, o, 64);
  __shared__ float pp[2];
  if ((t & 63) == 0) pp[t >> 6] = local;
  __syncthreads();
  if (t == 0) atomicAdd(&w[zid], pp[0] + pp[1]);
}

// ---------------------------------------------------------------------------
// Final (R5 form, proven): FIN_R=4 -> 500 blocks (2/CU); patient loads issued
// first; med loop unrolled x2; cvec fused into the simi GEMM f-loop.
// ---------------------------------------------------------------------------
constexpr int FIN_R = 4;   // P % FIN_R == 0 -> 500 blocks
__global__ __launch_bounds__(256) void k_final_all(
    const float* __restrict__ e0, const float* __restrict__ e1,
    const float* __restrict__ e2, const float* __restrict__ e3,
    const float* __restrict__ w, const float* __restrict__ outW,
    const float* __restrict__ outb,
    float* __restrict__ out_med, float* __restrict__ out_pat,
    float* __restrict__ simi) {
  int t = threadIdx.x;
  // betas
  float mm0 = w[2] * (1.f / M), mm1 = w[3] * (1.f / M);
  float mmx = fmaxf(mm0, mm1);
  float bm0 = expf(mm0 - mmx), bm1 = expf(mm1 - mmx);
  float msc = 1.f / (bm0 + bm1);
  bm0 *= msc; bm1 *= msc;
  float pm0 = w[0] * (1.f / P), pm1 = w[1] * (1.f / P);
  float pmx = fmaxf(pm0, pm1);
  float bp0 = expf(pm0 - pmx), bp1 = expf(pm1 - pmx);
  float psc = 1.f / (bp0 + bp1);
  bp0 *= psc; bp1 *= psc;
  // ---- patient rows: issue loads FIRST (FIN_R*64 == 256 -> one per thread) --
  int r0 = blockIdx.x * FIN_R;
  int pr = t >> 6, pln = t & 63;
  size_t poff = (size_t)(r0 + pr) * F + (pln << 2);
  float4 pu0 = *(const float4*)(e0 + poff);
  float4 pu1 = *(const float4*)(e1 + poff);
  // ---- med combine + relu col-sum, unrolled x2 (4 loads in flight) ----
  constexpr int MED4 = M * F / 4;   // 9600
  float4 rs = {0.f, 0.f, 0.f, 0.f};
  bool wr_med = (blockIdx.x == 0);
  for (int j = t; j < MED4; j += 512) {
    float4 u0 = ((const float4*)e2)[j], u1 = ((const float4*)e3)[j];
    float4 v0, v1;
    bool second = (j + 256) < MED4;
    if (second) { v0 = ((const float4*)e2)[j + 256]; v1 = ((const float4*)e3)[j + 256]; }
    float4 r = {bm0 * u0.x + bm1 * u1.x, bm0 * u0.y + bm1 * u1.y,
                bm0 * u0.z + bm1 * u1.z, bm0 * u0.w + bm1 * u1.w};
    if (wr_med) ((float4*)out_med)[j] = r;
    rs.x += r.x > 0.f ? r.x : 0.f;
    rs.y += r.y > 0.f ? r.y : 0.f;
    rs.z += r.z > 0.f ? r.z : 0.f;
    rs.w += r.w > 0.f ? r.w : 0.f;
    if (second) {
      float4 r2 = {bm0 * v0.x + bm1 * v1.x, bm0 * v0.y + bm1 * v1.y,
                   bm0 * v0.z + bm1 * v1.z, bm0 * v0.w + bm1 * v1.w};
      if (wr_med) ((float4*)out_med)[j + 256] = r2;
      rs.x += r2.x > 0.f ? r2.x : 0.f;
      rs.y += r2.y > 0.f ? r2.y : 0.f;
      rs.z += r2.z > 0.f ? r2.z : 0.f;
      rs.w += r2.w > 0.f ? r2.w : 0.f;
    }
  }
  // ---- patient combine written to LDS + out_pat (before sv barriers) ----
  __shared__ float psh[FIN_R][F];
  {
    float4 v = {bp0 * pu0.x + bp1 * pu1.x, bp0 * pu0.y + bp1 * pu1.y,
                bp0 * pu0.z + bp1 * pu1.z, bp0 * pu0.w + bp1 * pu1.w};
    *(float4*)(out_pat + poff) = v;
    v.x = v.x > 0.f ? v.x : 0.f; v.y = v.y > 0.f ? v.y : 0.f;
    v.z = v.z > 0.f ? v.z : 0.f; v.w = v.w > 0.f ? v.w : 0.f;
    *(float4*)&psh[pr][pln << 2] = v;
  }
  // ---- sv reduce (barriers also publish psh) ----
  __shared__ float4 sv4[4][64];
  sv4[t >> 6][t & 63] = rs;
  __syncthreads();
  __shared__ float sv[F];
  if (t < 64) {
    float4 a = sv4[0][t], b = sv4[1][t], c = sv4[2][t], d = sv4[3][t];
    sv[t * 4 + 0] = a.x + b.x + c.x + d.x;
    sv[t * 4 + 1] = a.y + b.y + c.y + d.y;
    sv[t * 4 + 2] = a.z + b.z + c.z + d.z;
    sv[t * 4 + 3] = a.w + b.w + c.w + d.w;
  }
  __syncthreads();
  // ---- fused cvec + simi GEMM: 8 outW loads, 5 acc chains per f-step ----
  if (t < M) {
    float acc[FIN_R];
#pragma unroll
    for (int r = 0; r < FIN_R; ++r) acc[r] = 0.f;
    float cv = (float)M * outb[t];
    for (int f = 0; f < F; f += 4) {
      float w0 = outW[(size_t)f * M + t],       w1 = outW[(size_t)(f + 1) * M + t],
            w2 = outW[(size_t)(f + 2) * M + t], w3 = outW[(size_t)(f + 3) * M + t];
      float b0 = outW[(size_t)(F + f) * M + t],     b1 = outW[(size_t)(F + f + 1) * M + t],
            b2 = outW[(size_t)(F + f + 2) * M + t], b3 = outW[(size_t)(F + f + 3) * M + t];
      cv += sv[f] * b0 + sv[f + 1] * b1 + sv[f + 2] * b2 + sv[f + 3] * b3;
#pragma unroll
      for (int r = 0; r < FIN_R; ++r) {
        float4 p4 = *(const float4*)&psh[r][f];
        acc[r] += p4.x * w0 + p4.y * w1 + p4.z * w2 + p4.w * w3;
      }
    }
#pragma unroll
    for (int r = 0; r < FIN_R; ++r)
      simi[(size_t)(r0 + r) * M + t] = (float)M * acc[r] + cv;
  }
}

// ---------------------------------------------------------------------------
extern "C" void kernel_launch(void* const* d_in, const int* in_sizes, int n_in,
                              void* d_out, int out_size, void* d_ws, size_t ws_size,
                              hipStream_t stream) {
  const int*   adj1_rows = (const int*)d_in[0];
  const int*   adj1_cols = (const int*)d_in[1];
  const float* adj1_vals = (const float*)d_in[2];
  const int*   adj2_rows = (const int*)d_in[3];
  const int*   adj2_cols = (const int*)d_in[4];
  const float* adj2_vals = (const float*)d_in[5];
  const int*   g0_src = (const int*)d_in[6];
  const int*   g0_dst = (const int*)d_in[7];
  const int*   g1_src = (const int*)d_in[8];
  const int*   g1_dst = (const int*)d_in[9];
  const int*   g2_src = (const int*)d_in[10];
  const int*   g2_dst = (const int*)d_in[11];
  const int*   g3_src = (const int*)d_in[12];
  const int*   g3_dst = (const int*)d_in[13];
  // d_in[14] = keepRate (unused, == 1)
  const float* pE     = (const float*)d_in[15];
  const float* mE     = (const float*)d_in[16];
  const float* dE     = (const float*)d_in[17];
  const float* gat_W  = (const float*)d_in[18];
  const float* gat_al = (const float*)d_in[19];
  const float* gat_ar = (const float*)d_in[20];
  const float* gat_b  = (const float*)d_in[21];
  const float* sa_W1  = (const float*)d_in[22];
  const float* sa_b1  = (const float*)d_in[23];
  const float* sa_W2  = (const float*)d_in[24];
  const float* out_W  = (const float*)d_in[25];
  const float* out_b  = (const float*)d_in[26];

  // ---- workspace layout: [zeroed (padded counters) | ELL | fp16 | fp32] ----
  int* ip = (int*)d_ws;
  int* cur1 = ip; ip += (size_t)N1 * CPAD;
  int* cur2 = ip; ip += (size_t)N2 * CPAD;
  int* cu0  = ip; ip += (size_t)P * CPAD;
  int* cu1  = ip; ip += (size_t)P * CPAD;
  int* cu2  = ip; ip += (size_t)M * CPAD;
  int* cu3  = ip; ip += (size_t)M * CPAD;
  int* ovf_n = ip; ip += 6;
  float* wbuf = (float*)ip; ip += 4;
  size_t memset_bytes = (size_t)((char*)ip - (char*)d_ws);

  uintptr_t up = ((uintptr_t)ip + 15) & ~(uintptr_t)15;
  int4* ovf = (int4*)up;                       // 6 * OVF_CAP
  uint2* ell1 = (uint2*)(ovf + 6 * OVF_CAP);   // N1 * CAP_A
  uint2* ell2 = ell1 + (size_t)N1 * CAP_A;     // N2 * CAP_A
  unsigned* eg0 = (unsigned*)(ell2 + (size_t)N2 * CAP_A);
  unsigned* eg1 = eg0 + (size_t)P * CAP_G;
  unsigned* eg2 = eg1 + (size_t)P * CAP_G;
  unsigned* eg3 = eg2 + (size_t)M * CAP_G;
  // fp16 region (16B-aligned by construction)
  __half* hp = (__half*)(eg3 + (size_t)M * CAP_G);
  __half* pEh   = hp; hp += (size_t)P * F;
  __half* mEh   = hp; hp += (size_t)M * F;
  __half* dEh   = hp; hp += (size_t)DG * F;
  __half* lat1h = hp; hp += (size_t)N1 * F;
  __half* lat2h = hp; hp += (size_t)N2 * F;
  __half* f0h   = hp; hp += (size_t)P * F;
  __half* f1h   = hp; hp += (size_t)P * F;
  __half* f2h   = hp; hp += (size_t)M * F;
  __half* f3h   = hp; hp += (size_t)M * F;
  float* fp = (float*)hp;
  float* lat1f = fp; fp += (size_t)N1 * F;
  float* lat2f = fp; fp += (size_t)N2 * F;
  float* acc1  = fp; fp += (size_t)N1 * F;
  float* acc2  = fp; fp += (size_t)N2 * F;
  float* el    = fp; fp += (size_t)(2 * P + 2 * M) * H;
  float* er    = fp; fp += (size_t)(2 * P + 2 * M) * H;
  float* e0b   = fp; fp += (size_t)P * F;
  float* e1b   = fp; fp += (size_t)P * F;
  float* e2b   = fp; fp += (size_t)M * F;
  float* e3b   = fp; fp += (size_t)M * F;

  // ---- output layout: (simi_pm, d_gcn, med, m_gcn, patient) ----
  float* out_simi = (float*)d_out;               // P*M
  float* out_dgcn = out_simi + (size_t)P * M;    // DG*F
  float* out_med  = out_dgcn + (size_t)DG * F;   // M*F
  float* out_mgcn = out_med  + (size_t)M * F;    // M*F
  float* out_pat  = out_mgcn + (size_t)M * F;    // P*F

  // ---- zero padded counters (~540 KB) ----
  hipMemsetAsync(d_ws, 0, memset_bytes, stream);

  // ---- ELL build + fused fp16 embed cast: ONE dispatch ----
  int eb = ((HOE + 3) / 4 + 255) / 256;
  k_build<<<eb, 256, 0, stream>>>(adj1_rows, adj1_cols, adj1_vals,
                                  adj2_rows, adj2_cols, adj2_vals,
                                  g0_dst, g0_src, g1_dst, g1_src,
                                  g2_dst, g2_src, g3_dst, g3_src,
                                  cur1, ell1, cur2, ell2,
                                  cu0, eg0, cu1, eg1, cu2, eg2, cu3, eg3,
                                  ovf_n, ovf,
                                  pE, mE, dE, pEh, mEh, dEh);

  // ---- GNN: 2 layers, 2 waves per row (edge-parity split, XCD swizzle) ----
  k_spmm<1><<<SPMM_NBLK, 256, 0, stream>>>(cur1, ell1, cur2, ell2, ovf_n, ovf,
                                           pEh, mEh, dEh, lat1f, lat2f, lat1h, lat2h,
                                           acc1, acc2, out_mgcn, out_dgcn);
  k_spmm<2><<<SPMM_NBLK, 256, 0, stream>>>(cur1, ell1, cur2, ell2, ovf_n, ovf,
                                           pEh, mEh, dEh, lat1f, lat2f, lat1h, lat2h,
                                           acc1, acc2, out_mgcn, out_dgcn);

  // ---- 4 GATs: scalar feature GEMM + 2-wave-split aggregation ----
  k_gat_feat_all<<<FEAT_BLOCKS, 256, 0, stream>>>(acc1, acc2, gat_W, gat_al, gat_ar,
                                                  f0h, f1h, f2h, f3h, el, er);
  int ab = (2 * P + 2 * M) / 2;   // 4300 groups * 128 threads / 256
  k_gat_agg_all<<<ab, 256, 0, stream>>>(cu0, eg0, cu1, eg1, cu2, eg2, cu3, eg3,
                                        ovf_n, ovf, el, er, f0h, f1h, f2h, f3h, gat_b,
                                        e0b, e1b, e2b, e3b);

  // ---- semantic attention weights ----
  k_sem_w_all<<<SEM_BLOCKS, 128, 0, stream>>>(e0b, e1b, e2b, e3b, sa_W1, sa_b1, sa_W2, wbuf);

  // ---- final: med+cvec+patient+simi fused (FIN_R=4, 500 blocks) ----
  k_final_all<<<P / FIN_R, 256, 0, stream>>>(e0b, e1b, e2b, e3b, wbuf, out_W, out_b,
                                             out_med, out_pat, out_simi);
}

// Round 9
// 299.335 us; speedup vs baseline: 1.1361x; 1.0171x over previous
//
#include <hip/hip_runtime.h>
#include <hip/hip_fp16.h>
#include <cmath>
#include <cstdint>

// Problem constants (fixed by the reference).
constexpr int P  = 2000, M = 150, DG = 2000, F = 256, H = 4, DH = 64;
constexpr int N1 = P + M;          // 2150
constexpr int N2 = P + DG;         // 4000
constexpr int E1 = 137600, E2 = 256000, EGP = 64000, EGM = 4800;
constexpr int SA_HID = 128;

// Edge-range offsets for the fused build kernel.
constexpr int HO1 = E1, HO2 = E1 + E2, HO3 = HO2 + EGP, HO4 = HO3 + EGP,
              HO5 = HO4 + EGM, HOE = HO5 + EGM;   // 531200 total edges

// ELL capacities (overflow list guarantees correctness regardless).
constexpr int CAP_A = 160;
constexpr int CAP_G = 96;
constexpr int OVF_CAP = 4096;

// One counter per 64B line (R7: removed same-line atomic serialization).
constexpr int CPAD = 16;

// ---- fp16 helpers -----------------------------------------------------------
__device__ __forceinline__ float4 h4_to_f4(const __half* p) {
  union { ushort4 u4; __half2 h2[2]; } u;
  u.u4 = *(const ushort4*)p;
  float2 lo = __half22float2(u.h2[0]);
  float2 hi = __half22float2(u.h2[1]);
  return make_float4(lo.x, lo.y, hi.x, hi.y);
}
__device__ __forceinline__ void f4_to_h4(__half* p, float4 v) {
  union { ushort4 u4; __half2 h2[2]; } u;
  u.h2[0] = __float22half2_rn(make_float2(v.x, v.y));
  u.h2[1] = __float22half2_rn(make_float2(v.z, v.w));
  *(ushort4*)p = u.u4;
}

// ---------------------------------------------------------------------------
// ELL build (padded counters) + fused fp32->fp16 embed cast.
// ---------------------------------------------------------------------------
constexpr int CAST_CH = (P * F + M * F + DG * F) / 8;   // 8-float chunks

__global__ __launch_bounds__(256) void k_build(
    const int* __restrict__ a1r, const int* __restrict__ a1c, const float* __restrict__ a1v,
    const int* __restrict__ a2r, const int* __restrict__ a2c, const float* __restrict__ a2v,
    const int* __restrict__ d0, const int* __restrict__ s0,
    const int* __restrict__ d1, const int* __restrict__ s1,
    const int* __restrict__ d2, const int* __restrict__ s2,
    const int* __restrict__ d3, const int* __restrict__ s3,
    int* cur1, uint2* ell1, int* cur2, uint2* ell2,
    int* cu0, unsigned* eg0, int* cu1, unsigned* eg1,
    int* cu2, unsigned* eg2, int* cu3, unsigned* eg3,
    int* __restrict__ ovf_n, int4* __restrict__ ovf,
    const float* __restrict__ pEf, const float* __restrict__ mEf,
    const float* __restrict__ dEf,
    __half* __restrict__ pEh, __half* __restrict__ mEh, __half* __restrict__ dEh) {
  int tid = blockIdx.x * 256 + threadIdx.x;
  int T = gridDim.x * 256;
  int seg[4], row[4]; unsigned p0[4], p1[4];
#pragma unroll
  for (int u = 0; u < 4; ++u) {
    int i = tid + u * T;
    seg[u] = -1;
    if (i < HOE) {
      if (i < HO1)      { seg[u] = 0; row[u] = a1r[i]; p0[u] = (unsigned)a1c[i]; p1[u] = __float_as_uint(a1v[i]); }
      else if (i < HO2) { int j = i - HO1; seg[u] = 1; row[u] = a2r[j]; p0[u] = (unsigned)a2c[j]; p1[u] = __float_as_uint(a2v[j]); }
      else if (i < HO3) { int j = i - HO2; seg[u] = 2; row[u] = d0[j]; p0[u] = (unsigned)s0[j]; }
      else if (i < HO4) { int j = i - HO3; seg[u] = 3; row[u] = d1[j]; p0[u] = (unsigned)s1[j]; }
      else if (i < HO5) { int j = i - HO4; seg[u] = 4; row[u] = d2[j]; p0[u] = (unsigned)s2[j]; }
      else              { int j = i - HO5; seg[u] = 5; row[u] = d3[j]; p0[u] = (unsigned)s3[j]; }
    }
  }
#pragma unroll
  for (int u = 0; u < 4; ++u) {
    int r = row[u];
    switch (seg[u]) {
      case 0: { int slot = atomicAdd(&cur1[(size_t)r * CPAD], 1);
        if (slot < CAP_A) ell1[(size_t)r * CAP_A + slot] = make_uint2(p0[u], p1[u]);
        else { int o = atomicAdd(&ovf_n[0], 1); if (o < OVF_CAP) ovf[0 * OVF_CAP + o] = make_int4(r, (int)p0[u], (int)p1[u], 0); } } break;
      case 1: { int slot = atomicAdd(&cur2[(size_t)r * CPAD], 1);
        if (slot < CAP_A) ell2[(size_t)r * CAP_A + slot] = make_uint2(p0[u], p1[u]);
        else { int o = atomicAdd(&ovf_n[1], 1); if (o < OVF_CAP) ovf[1 * OVF_CAP + o] = make_int4(r, (int)p0[u], (int)p1[u], 0); } } break;
      case 2: { int slot = atomicAdd(&cu0[(size_t)r * CPAD], 1);
        if (slot < CAP_G) eg0[(size_t)r * CAP_G + slot] = p0[u];
        else { int o = atomicAdd(&ovf_n[2], 1); if (o < OVF_CAP) ovf[2 * OVF_CAP + o] = make_int4(r, (int)p0[u], 0, 0); } } break;
      case 3: { int slot = atomicAdd(&cu1[(size_t)r * CPAD], 1);
        if (slot < CAP_G) eg1[(size_t)r * CAP_G + slot] = p0[u];
        else { int o = atomicAdd(&ovf_n[3], 1); if (o < OVF_CAP) ovf[3 * OVF_CAP + o] = make_int4(r, (int)p0[u], 0, 0); } } break;
      case 4: { int slot = atomicAdd(&cu2[(size_t)r * CPAD], 1);
        if (slot < CAP_G) eg2[(size_t)r * CAP_G + slot] = p0[u];
        else { int o = atomicAdd(&ovf_n[4], 1); if (o < OVF_CAP) ovf[4 * OVF_CAP + o] = make_int4(r, (int)p0[u], 0, 0); } } break;
      case 5: { int slot = atomicAdd(&cu3[(size_t)r * CPAD], 1);
        if (slot < CAP_G) eg3[(size_t)r * CAP_G + slot] = p0[u];
        else { int o = atomicAdd(&ovf_n[5], 1); if (o < OVF_CAP) ovf[5 * OVF_CAP + o] = make_int4(r, (int)p0[u], 0, 0); } } break;
      default: break;
    }
  }
  // Fused embed cast fp32 -> fp16 (independent streaming work).
  for (int c = tid; c < CAST_CH; c += T) {
    int j = c * 8;
    const float* src; __half* dst;
    if (j < P * F)              { src = pEf + j;               dst = pEh + j; }
    else if (j < P * F + M * F) { src = mEf + (j - P * F);     dst = mEh + (j - P * F); }
    else                        { src = dEf + (j - P*F - M*F); dst = dEh + (j - P*F - M*F); }
    float4 a = *(const float4*)src, b = *(const float4*)(src + 4);
    f4_to_h4(dst, a);
    f4_to_h4(dst + 4, b);
  }
}

// ---------------------------------------------------------------------------
// SPMM (R9): ONE wave per row (4 rows per 256-thread block) — removes the
// 2-wave parity split's LDS combine + 2 barriers + wave-1 early exits.
// Same proven 8-edge in-flight gather batch. XCD swizzle kept (free).
// ---------------------------------------------------------------------------
constexpr int SPMM_GROUPS = N1 + N2;                 // 6150
constexpr int SPMM_NBLK = (SPMM_GROUPS + 3) / 4;     // 1538
template<int LAYER>
__global__ __launch_bounds__(256) void k_spmm(
    const int* __restrict__ cur1, const uint2* __restrict__ ell1,
    const int* __restrict__ cur2, const uint2* __restrict__ ell2,
    const int* __restrict__ ovf_n, const int4* __restrict__ ovf,
    const __half* __restrict__ pEh, const __half* __restrict__ mEh,
    const __half* __restrict__ dEh,
    float* __restrict__ lat1f, float* __restrict__ lat2f,
    __half* __restrict__ lat1h, __half* __restrict__ lat2h,
    float* __restrict__ acc1, float* __restrict__ acc2,
    float* __restrict__ out_mgcn, float* __restrict__ out_dgcn) {
  // Bijective XCD swizzle (nb=1538, nb%8=2): XCD k gets a contiguous chunk.
  constexpr int Q = SPMM_NBLK / 8, Rr = SPMM_NBLK % 8;
  int xcd = blockIdx.x & 7, idx = blockIdx.x >> 3;
  int swz = (xcd < Rr) ? xcd * (Q + 1) + idx : Rr * (Q + 1) + (xcd - Rr) * Q + idx;
  int grp = swz * 4 + (threadIdx.x >> 6);            // row id (1 wave per row)
  if (grp >= SPMM_GROUPS) return;
  int lane = threadIdx.x & 63;
  bool g2 = grp >= N1;
  int row = g2 ? grp - N1 : grp;
  const uint2* pe = (g2 ? ell2 : ell1) + (size_t)row * CAP_A;
  const __half* latinh = g2 ? lat2h : lat1h;
  const __half* tailEh = g2 ? dEh : mEh;
  int deg = (g2 ? cur2 : cur1)[(size_t)row * CPAD];
  int dn = deg < CAP_A ? deg : CAP_A;
  int fo = lane << 2;
  float4 s = {0.f, 0.f, 0.f, 0.f};
  auto fetch = [&](int c) -> float4 {
    const __half* b;
    if (LAYER == 1) b = (c < P) ? (pEh + (size_t)c * F) : (tailEh + (size_t)(c - P) * F);
    else            b = latinh + (size_t)c * F;
    return h4_to_f4(b + fo);
  };
  int i = 0;
  for (; i + 8 <= dn; i += 8) {      // 8 edges in flight
    uint2 m[8]; float4 a[8];
#pragma unroll
    for (int u = 0; u < 8; ++u) m[u] = pe[i + u];
#pragma unroll
    for (int u = 0; u < 8; ++u) a[u] = fetch((int)m[u].x);
#pragma unroll
    for (int u = 0; u < 8; ++u) {
      float v = __uint_as_float(m[u].y);
      s.x += v * a[u].x; s.y += v * a[u].y; s.z += v * a[u].z; s.w += v * a[u].w;
    }
  }
  for (; i < dn; ++i) {
    uint2 m = pe[i];
    float v = __uint_as_float(m.y);
    float4 a = fetch((int)m.x);
    s.x += v * a.x; s.y += v * a.y; s.z += v * a.z; s.w += v * a.w;
  }
  // Overflow edges (normally zero).
  {
    int gi = g2 ? 1 : 0;
    int on = ovf_n[gi];
    if (on > 0) {
      const int4* ol = ovf + gi * OVF_CAP;
      for (int k = 0; k < on; ++k) {
        int4 e = ol[k];
        if (e.x == row) {
          float v = __int_as_float(e.z);
          float4 a = fetch(e.y);
          s.x += v * a.x; s.y += v * a.y; s.z += v * a.z; s.w += v * a.w;
        }
      }
    }
  }
  float4 l;
  l.x = s.x > 0.f ? s.x : 0.5f * s.x;
  l.y = s.y > 0.f ? s.y : 0.5f * s.y;
  l.z = s.z > 0.f ? s.z : 0.5f * s.z;
  l.w = s.w > 0.f ? s.w : 0.5f * s.w;
  if (LAYER == 1) {
    *(float4*)((g2 ? lat2f : lat1f) + (size_t)row * F + fo) = l;   // exact own-row
    f4_to_h4((g2 ? lat2h : lat1h) + (size_t)row * F + fo, l);      // gather copy
  } else {
    const float* latf = g2 ? lat2f : lat1f;
    float4 b = *(const float4*)(latf + (size_t)row * F + fo);
    float4 a = {b.x + l.x, b.y + l.y, b.z + l.z, b.w + l.w};
    *(float4*)((g2 ? acc2 : acc1) + (size_t)row * F + fo) = a;
    if (row >= P)
      *(float4*)((g2 ? out_dgcn : out_mgcn) + (size_t)(row - P) * F + fo) = a;
  }
}

// ---------------------------------------------------------------------------
// All 4 GAT feature GEMMs. FR=8 (R8/R9: occupancy beats W-traffic reduction).
// ---------------------------------------------------------------------------
constexpr int FR  = 8;
constexpr int NB0 = (P + FR - 1) / FR;   // 250
constexpr int NB2 = (M + FR - 1) / FR;   // 19
constexpr int FEAT_BLOCKS = 2 * NB0 + 2 * NB2;

__global__ __launch_bounds__(256) void k_gat_feat_all(
    const float* __restrict__ acc1, const float* __restrict__ acc2,
    const float* __restrict__ gat_W, const float* __restrict__ gat_al,
    const float* __restrict__ gat_ar,
    __half* __restrict__ f0, __half* __restrict__ f1,
    __half* __restrict__ f2, __half* __restrict__ f3,
    float* __restrict__ el, float* __restrict__ er) {
  int b = blockIdx.x;
  int g, rb, n; const float* h; __half* fout;
  if (b < NB0)            { g = 0; rb = b;              n = P; h = acc1; fout = f0; }
  else if (b < 2 * NB0)   { g = 1; rb = b - NB0;        n = P; h = acc2; fout = f1; }
  else if (b < 2*NB0+NB2) { g = 2; rb = b - 2 * NB0;    n = M; h = acc1 + (size_t)P * F; fout = f2; }
  else                    { g = 3; rb = b - 2*NB0 - NB2; n = M; h = acc1 + (size_t)P * F; fout = f3; }
  int elo = (g == 0) ? 0 : (g == 1) ? P * H : (g == 2) ? 2 * P * H : (2 * P + M) * H;
  const float* W = gat_W + (size_t)g * F * F;
  __shared__ float hs[FR][F];
  int t = threadIdx.x;
  int r0 = rb * FR;
  for (int q = t; q < FR * 64; q += 256) {
    int r = q >> 6, ln = q & 63;
    int row = r0 + r;
    float4 v = {0.f, 0.f, 0.f, 0.f};
    if (row < n) v = *(const float4*)(h + (size_t)row * F + (ln << 2));
    *(float4*)&hs[r][ln << 2] = v;
  }
  __syncthreads();
  float acc[FR];
#pragma unroll
  for (int r = 0; r < FR; ++r) acc[r] = 0.f;
  for (int k = 0; k < F; k += 4) {
    float w0 = W[(size_t)k * F + t],       w1 = W[(size_t)(k + 1) * F + t],
          w2 = W[(size_t)(k + 2) * F + t], w3 = W[(size_t)(k + 3) * F + t];
#pragma unroll
    for (int r = 0; r < FR; ++r) {
      float4 h4 = *(const float4*)&hs[r][k];
      acc[r] += h4.x * w0 + h4.y * w1 + h4.z * w2 + h4.w * w3;
    }
  }
  int head = t >> 6, d = t & 63;           // one wave == one head
  float av = gat_al[g * H * DH + head * DH + d];
  float rv = gat_ar[g * H * DH + head * DH + d];
#pragma unroll
  for (int r = 0; r < FR; ++r) {
    int row = r0 + r;
    if (row < n) {
      fout[(size_t)row * F + t] = __float2half_rn(acc[r]);
      float cl = acc[r] * av, cr = acc[r] * rv;
      for (int o = 32; o > 0; o >>= 1) {
        cl += __shfl_down(cl, o, 64);
        cr += __shfl_down(cr, o, 64);
      }
      if (d == 0) { el[elo + row * H + head] = cl; er[elo + row * H + head] = cr; }
    }
  }
}

// ---------------------------------------------------------------------------
// All 4 GAT aggregations: TWO waves per dst-row (edge-parity split).
// R9: both passes deepened to 8 edges in flight (VGPR stays ~50, free MLP).
// ---------------------------------------------------------------------------
__global__ __launch_bounds__(256) void k_gat_agg_all(
    const int* __restrict__ cu0, const unsigned* __restrict__ eg0,
    const int* __restrict__ cu1, const unsigned* __restrict__ eg1,
    const int* __restrict__ cu2, const unsigned* __restrict__ eg2,
    const int* __restrict__ cu3, const unsigned* __restrict__ eg3,
    const int* __restrict__ ovf_n, const int4* __restrict__ ovf,
    const float* __restrict__ el, const float* __restrict__ er,
    const __half* __restrict__ f0, const __half* __restrict__ f1,
    const __half* __restrict__ f2, const __half* __restrict__ f3,
    const float* __restrict__ gat_b,
    float* __restrict__ e0, float* __restrict__ e1,
    float* __restrict__ e2, float* __restrict__ e3) {
  int grp = (blockIdx.x * 256 + threadIdx.x) >> 7;
  int lane = threadIdx.x & 63;
  int wh   = (threadIdx.x >> 6) & 1;
  int gl   = threadIdx.x >> 7;
  int g, row; const int* cu; const unsigned* eg; const __half* feat; float* out; int elo;
  if (grp < P)            { g = 0; row = grp;             cu = cu0; eg = eg0; feat = f0; out = e0; elo = 0; }
  else if (grp < 2 * P)   { g = 1; row = grp - P;         cu = cu1; eg = eg1; feat = f1; out = e1; elo = P * H; }
  else if (grp < 2*P + M) { g = 2; row = grp - 2 * P;     cu = cu2; eg = eg2; feat = f2; out = e2; elo = 2 * P * H; }
  else                    { g = 3; row = grp - 2 * P - M; cu = cu3; eg = eg3; feat = f3; out = e3; elo = (2 * P + M) * H; }
  int head = lane >> 4;
  int fo = lane << 2;
  const float* elb = el + elo;
  float erv = er[elo + row * H + head];
  int deg = cu[(size_t)row * CPAD];
  int dn = deg < CAP_G ? deg : CAP_G;
  const unsigned* ps = eg + (size_t)row * CAP_G;
  int on = ovf_n[2 + g];
  const int4* ol = ovf + (2 + g) * OVF_CAP;
  // ---- pass 1: max over this wave's parity edges, 8 score loads in flight --
  float mx = -3.4e38f;
  int i = wh;
  for (; i + 15 <= dn; i += 16) {   // 8 edges: i, i+2, ..., i+14
    int sx[8]; float vv[8];
#pragma unroll
    for (int u = 0; u < 8; ++u) sx[u] = (int)ps[i + 2 * u];
#pragma unroll
    for (int u = 0; u < 8; ++u) vv[u] = elb[sx[u] * H + head] + erv;
#pragma unroll
    for (int u = 0; u < 8; ++u) { float a = vv[u]; a = a > 0.f ? a : 0.2f * a; mx = fmaxf(mx, a); }
  }
  for (; i < dn; i += 2) {
    float a = elb[(int)ps[i] * H + head] + erv;
    a = a > 0.f ? a : 0.2f * a;
    mx = fmaxf(mx, a);
  }
  if (wh == 0 && on > 0) {
    for (int k = 0; k < on; ++k) {
      int4 e = ol[k];
      if (e.x == row) {
        float a = elb[e.y * H + head] + erv;
        a = a > 0.f ? a : 0.2f * a;
        mx = fmaxf(mx, a);
      }
    }
  }
  __shared__ float mxs[2][2][64];
  mxs[gl][wh][lane] = mx;
  __syncthreads();
  mx = fmaxf(mxs[gl][0][lane], mxs[gl][1][lane]);
  // ---- pass 2: exp-sum + weighted aggregation, 8 gathers in flight ----
  float ssum = 0.f;
  float4 acc = {0.f, 0.f, 0.f, 0.f};
  i = wh;
  for (; i + 15 <= dn; i += 16) {   // 8 edges
    int sx[8]; float xs[8]; float4 q[8];
#pragma unroll
    for (int u = 0; u < 8; ++u) sx[u] = (int)ps[i + 2 * u];
#pragma unroll
    for (int u = 0; u < 8; ++u) q[u] = h4_to_f4(feat + (size_t)sx[u] * F + fo);
#pragma unroll
    for (int u = 0; u < 8; ++u) {
      float a = elb[sx[u] * H + head] + erv; a = a > 0.f ? a : 0.2f * a;
      xs[u] = expf(a - mx);
    }
#pragma unroll
    for (int u = 0; u < 8; ++u) {
      ssum += xs[u];
      acc.x += xs[u] * q[u].x; acc.y += xs[u] * q[u].y;
      acc.z += xs[u] * q[u].z; acc.w += xs[u] * q[u].w;
    }
  }
  for (; i + 3 <= dn; i += 4) {     // 2 edges
    int s0 = (int)ps[i], s1 = (int)ps[i + 2];
    float a = elb[s0 * H + head] + erv; a = a > 0.f ? a : 0.2f * a;
    float b = elb[s1 * H + head] + erv; b = b > 0.f ? b : 0.2f * b;
    float x0 = expf(a - mx), x1 = expf(b - mx);
    float4 q0 = h4_to_f4(feat + (size_t)s0 * F + fo);
    float4 q1 = h4_to_f4(feat + (size_t)s1 * F + fo);
    ssum += x0 + x1;
    acc.x += x0 * q0.x + x1 * q1.x;
    acc.y += x0 * q0.y + x1 * q1.y;
    acc.z += x0 * q0.z + x1 * q1.z;
    acc.w += x0 * q0.w + x1 * q1.w;
  }
  for (; i < dn; i += 2) {
    int s0 = (int)ps[i];
    float a = elb[s0 * H + head] + erv; a = a > 0.f ? a : 0.2f * a;
    float x0 = expf(a - mx);
    float4 q0 = h4_to_f4(feat + (size_t)s0 * F + fo);
    ssum += x0;
    acc.x += x0 * q0.x; acc.y += x0 * q0.y; acc.z += x0 * q0.z; acc.w += x0 * q0.w;
  }
  __shared__ float4 pacc[2][64];
  __shared__ float  pss[2][64];
  if (wh == 1) { pacc[gl][lane] = acc; pss[gl][lane] = ssum; }
  __syncthreads();
  if (wh == 1) return;
  {
    float4 pa = pacc[gl][lane];
    acc.x += pa.x; acc.y += pa.y; acc.z += pa.z; acc.w += pa.w;
    ssum += pss[gl][lane];
  }
  if (on > 0) {
    for (int k = 0; k < on; ++k) {
      int4 e = ol[k];
      if (e.x == row) {
        float a = elb[e.y * H + head] + erv; a = a > 0.f ? a : 0.2f * a;
        float x0 = expf(a - mx);
        float4 q0 = h4_to_f4(feat + (size_t)e.y * F + fo);
        ssum += x0;
        acc.x += x0 * q0.x; acc.y += x0 * q0.y; acc.z += x0 * q0.z; acc.w += x0 * q0.w;
      }
    }
  }
  float inv = 1.f / (ssum + 1e-9f);
  const float* bb = gat_b + g * F + fo;
  float4 v = {acc.x * inv + bb[0], acc.y * inv + bb[1],
              acc.z * inv + bb[2], acc.w * inv + bb[3]};
  v.x = v.x > 0.f ? v.x : expm1f(v.x);
  v.y = v.y > 0.f ? v.y : expm1f(v.y);
  v.z = v.z > 0.f ? v.z : expm1f(v.z);
  v.w = v.w > 0.f ? v.w : expm1f(v.w);
  *(float4*)(out + (size_t)row * F + fo) = v;
}

// ---------------------------------------------------------------------------
// Semantic attention weights. SR=4 (proven: W1 amortized over 4 rows, 4 ILP
// chains per load).
// ---------------------------------------------------------------------------
constexpr int SR  = 4;
constexpr int SB0 = (P + SR - 1) / SR;   // 500
constexpr int SB2 = (M + SR - 1) / SR;   // 38
constexpr int SEM_BLOCKS = 2 * SB0 + 2 * SB2;

__global__ __launch_bounds__(128) void k_sem_w_all(
    const float* __restrict__ e0, const float* __restrict__ e1,
    const float* __restrict__ e2, const float* __restrict__ e3,
    const float* __restrict__ W1, const float* __restrict__ b1,
    const float* __restrict__ W2, float* __restrict__ w) {
  int b = blockIdx.x;
  int zid, rb, n; const float* z;
  if (b < SB0)            { zid = 0; rb = b;             n = P; z = e0; }
  else if (b < 2 * SB0)   { zid = 1; rb = b - SB0;       n = P; z = e1; }
  else if (b < 2*SB0+SB2) { zid = 2; rb = b - 2 * SB0;   n = M; z = e2; }
  else                    { zid = 3; rb = b - 2*SB0-SB2; n = M; z = e3; }
  __shared__ float zs[SR][F];
  int t = threadIdx.x;
  int r0 = rb * SR;
  for (int q = t; q < SR * 64; q += 128) {
    int r = q >> 6, ln = q & 63;
    int row = r0 + r;
    float4 v = {0.f, 0.f, 0.f, 0.f};
    if (row < n) v = *(const float4*)(z + (size_t)row * F + (ln << 2));
    *(float4*)&zs[r][ln << 2] = v;
  }
  __syncthreads();
  float hid[SR];
#pragma unroll
  for (int r = 0; r < SR; ++r) hid[r] = b1[t];
  for (int k = 0; k < F; k += 4) {
    float w0 = W1[(size_t)k * SA_HID + t],       w1 = W1[(size_t)(k + 1) * SA_HID + t],
          w2 = W1[(size_t)(k + 2) * SA_HID + t], w3 = W1[(size_t)(k + 3) * SA_HID + t];
#pragma unroll
    for (int r = 0; r < SR; ++r) {
      float4 z4 = *(const float4*)&zs[r][k];
      hid[r] += z4.x * w0 + z4.y * w1 + z4.z * w2 + z4.w * w3;
    }
  }
  float w2v = W2[t];
  float local = 0.f;
  for (int r = 0; r < SR; ++r) {
    int row = r0 + r;
    if (row < n) local += tanhf(hid[r]) * w2v;
  }
  for (int o = 32; o > 0; o >>= 1) local += __shfl_down(local, o, 64);
  __shared__ float pp[2];
  if ((t & 63) == 0) pp[t >> 6] = local;
  __syncthreads();
  if (t == 0) atomicAdd(&w[zid], pp[0] + pp[1]);
}

// ---------------------------------------------------------------------------
// Final (R5 form, proven): FIN_R=4 -> 500 blocks (2/CU); patient loads issued
// first; med loop unrolled x2; cvec fused into the simi GEMM f-loop.
// ---------------------------------------------------------------------------
constexpr int FIN_R = 4;   // P % FIN_R == 0 -> 500 blocks
__global__ __launch_bounds__(256) void k_final_all(
    const float* __restrict__ e0, const float* __restrict__ e1,
    const float* __restrict__ e2, const float* __restrict__ e3,
    const float* __restrict__ w, const float* __restrict__ outW,
    const float* __restrict__ outb,
    float* __restrict__ out_med, float* __restrict__ out_pat,
    float* __restrict__ simi) {
  int t = threadIdx.x;
  // betas
  float mm0 = w[2] * (1.f / M), mm1 = w[3] * (1.f / M);
  float mmx = fmaxf(mm0, mm1);
  float bm0 = expf(mm0 - mmx), bm1 = expf(mm1 - mmx);
  float msc = 1.f / (bm0 + bm1);
  bm0 *= msc; bm1 *= msc;
  float pm0 = w[0] * (1.f / P), pm1 = w[1] * (1.f / P);
  float pmx = fmaxf(pm0, pm1);
  float bp0 = expf(pm0 - pmx), bp1 = expf(pm1 - pmx);
  float psc = 1.f / (bp0 + bp1);
  bp0 *= psc; bp1 *= psc;
  // ---- patient rows: issue loads FIRST (FIN_R*64 == 256 -> one per thread) --
  int r0 = blockIdx.x * FIN_R;
  int pr = t >> 6, pln = t & 63;
  size_t poff = (size_t)(r0 + pr) * F + (pln << 2);
  float4 pu0 = *(const float4*)(e0 + poff);
  float4 pu1 = *(const float4*)(e1 + poff);
  // ---- med combine + relu col-sum, unrolled x2 (4 loads in flight) ----
  constexpr int MED4 = M * F / 4;   // 9600
  float4 rs = {0.f, 0.f, 0.f, 0.f};
  bool wr_med = (blockIdx.x == 0);
  for (int j = t; j < MED4; j += 512) {
    float4 u0 = ((const float4*)e2)[j], u1 = ((const float4*)e3)[j];
    float4 v0, v1;
    bool second = (j + 256) < MED4;
    if (second) { v0 = ((const float4*)e2)[j + 256]; v1 = ((const float4*)e3)[j + 256]; }
    float4 r = {bm0 * u0.x + bm1 * u1.x, bm0 * u0.y + bm1 * u1.y,
                bm0 * u0.z + bm1 * u1.z, bm0 * u0.w + bm1 * u1.w};
    if (wr_med) ((float4*)out_med)[j] = r;
    rs.x += r.x > 0.f ? r.x : 0.f;
    rs.y += r.y > 0.f ? r.y : 0.f;
    rs.z += r.z > 0.f ? r.z : 0.f;
    rs.w += r.w > 0.f ? r.w : 0.f;
    if (second) {
      float4 r2 = {bm0 * v0.x + bm1 * v1.x, bm0 * v0.y + bm1 * v1.y,
                   bm0 * v0.z + bm1 * v1.z, bm0 * v0.w + bm1 * v1.w};
      if (wr_med) ((float4*)out_med)[j + 256] = r2;
      rs.x += r2.x > 0.f ? r2.x : 0.f;
      rs.y += r2.y > 0.f ? r2.y : 0.f;
      rs.z += r2.z > 0.f ? r2.z : 0.f;
      rs.w += r2.w > 0.f ? r2.w : 0.f;
    }
  }
  // ---- patient combine written to LDS + out_pat (before sv barriers) ----
  __shared__ float psh[FIN_R][F];
  {
    float4 v = {bp0 * pu0.x + bp1 * pu1.x, bp0 * pu0.y + bp1 * pu1.y,
                bp0 * pu0.z + bp1 * pu1.z, bp0 * pu0.w + bp1 * pu1.w};
    *(float4*)(out_pat + poff) = v;
    v.x = v.x > 0.f ? v.x : 0.f; v.y = v.y > 0.f ? v.y : 0.f;
    v.z = v.z > 0.f ? v.z : 0.f; v.w = v.w > 0.f ? v.w : 0.f;
    *(float4*)&psh[pr][pln << 2] = v;
  }
  // ---- sv reduce (barriers also publish psh) ----
  __shared__ float4 sv4[4][64];
  sv4[t >> 6][t & 63] = rs;
  __syncthreads();
  __shared__ float sv[F];
  if (t < 64) {
    float4 a = sv4[0][t], b = sv4[1][t], c = sv4[2][t], d = sv4[3][t];
    sv[t * 4 + 0] = a.x + b.x + c.x + d.x;
    sv[t * 4 + 1] = a.y + b.y + c.y + d.y;
    sv[t * 4 + 2] = a.z + b.z + c.z + d.z;
    sv[t * 4 + 3] = a.w + b.w + c.w + d.w;
  }
  __syncthreads();
  // ---- fused cvec + simi GEMM: 8 outW loads, 5 acc chains per f-step ----
  if (t < M) {
    float acc[FIN_R];
#pragma unroll
    for (int r = 0; r < FIN_R; ++r) acc[r] = 0.f;
    float cv = (float)M * outb[t];
    for (int f = 0; f < F; f += 4) {
      float w0 = outW[(size_t)f * M + t],       w1 = outW[(size_t)(f + 1) * M + t],
            w2 = outW[(size_t)(f + 2) * M + t], w3 = outW[(size_t)(f + 3) * M + t];
      float b0 = outW[(size_t)(F + f) * M + t],     b1 = outW[(size_t)(F + f + 1) * M + t],
            b2 = outW[(size_t)(F + f + 2) * M + t], b3 = outW[(size_t)(F + f + 3) * M + t];
      cv += sv[f] * b0 + sv[f + 1] * b1 + sv[f + 2] * b2 + sv[f + 3] * b3;
#pragma unroll
      for (int r = 0; r < FIN_R; ++r) {
        float4 p4 = *(const float4*)&psh[r][f];
        acc[r] += p4.x * w0 + p4.y * w1 + p4.z * w2 + p4.w * w3;
      }
    }
#pragma unroll
    for (int r = 0; r < FIN_R; ++r)
      simi[(size_t)(r0 + r) * M + t] = (float)M * acc[r] + cv;
  }
}

// ---------------------------------------------------------------------------
extern "C" void kernel_launch(void* const* d_in, const int* in_sizes, int n_in,
                              void* d_out, int out_size, void* d_ws, size_t ws_size,
                              hipStream_t stream) {
  const int*   adj1_rows = (const int*)d_in[0];
  const int*   adj1_cols = (const int*)d_in[1];
  const float* adj1_vals = (const float*)d_in[2];
  const int*   adj2_rows = (const int*)d_in[3];
  const int*   adj2_cols = (const int*)d_in[4];
  const float* adj2_vals = (const float*)d_in[5];
  const int*   g0_src = (const int*)d_in[6];
  const int*   g0_dst = (const int*)d_in[7];
  const int*   g1_src = (const int*)d_in[8];
  const int*   g1_dst = (const int*)d_in[9];
  const int*   g2_src = (const int*)d_in[10];
  const int*   g2_dst = (const int*)d_in[11];
  const int*   g3_src = (const int*)d_in[12];
  const int*   g3_dst = (const int*)d_in[13];
  // d_in[14] = keepRate (unused, == 1)
  const float* pE     = (const float*)d_in[15];
  const float* mE     = (const float*)d_in[16];
  const float* dE     = (const float*)d_in[17];
  const float* gat_W  = (const float*)d_in[18];
  const float* gat_al = (const float*)d_in[19];
  const float* gat_ar = (const float*)d_in[20];
  const float* gat_b  = (const float*)d_in[21];
  const float* sa_W1  = (const float*)d_in[22];
  const float* sa_b1  = (const float*)d_in[23];
  const float* sa_W2  = (const float*)d_in[24];
  const float* out_W  = (const float*)d_in[25];
  const float* out_b  = (const float*)d_in[26];

  // ---- workspace layout: [zeroed (padded counters) | ELL | fp16 | fp32] ----
  int* ip = (int*)d_ws;
  int* cur1 = ip; ip += (size_t)N1 * CPAD;
  int* cur2 = ip; ip += (size_t)N2 * CPAD;
  int* cu0  = ip; ip += (size_t)P * CPAD;
  int* cu1  = ip; ip += (size_t)P * CPAD;
  int* cu2  = ip; ip += (size_t)M * CPAD;
  int* cu3  = ip; ip += (size_t)M * CPAD;
  int* ovf_n = ip; ip += 6;
  float* wbuf = (float*)ip; ip += 4;
  size_t memset_bytes = (size_t)((char*)ip - (char*)d_ws);

  uintptr_t up = ((uintptr_t)ip + 15) & ~(uintptr_t)15;
  int4* ovf = (int4*)up;                       // 6 * OVF_CAP
  uint2* ell1 = (uint2*)(ovf + 6 * OVF_CAP);   // N1 * CAP_A
  uint2* ell2 = ell1 + (size_t)N1 * CAP_A;     // N2 * CAP_A
  unsigned* eg0 = (unsigned*)(ell2 + (size_t)N2 * CAP_A);
  unsigned* eg1 = eg0 + (size_t)P * CAP_G;
  unsigned* eg2 = eg1 + (size_t)P * CAP_G;
  unsigned* eg3 = eg2 + (size_t)M * CAP_G;
  // fp16 region (16B-aligned by construction)
  __half* hp = (__half*)(eg3 + (size_t)M * CAP_G);
  __half* pEh   = hp; hp += (size_t)P * F;
  __half* mEh   = hp; hp += (size_t)M * F;
  __half* dEh   = hp; hp += (size_t)DG * F;
  __half* lat1h = hp; hp += (size_t)N1 * F;
  __half* lat2h = hp; hp += (size_t)N2 * F;
  __half* f0h   = hp; hp += (size_t)P * F;
  __half* f1h   = hp; hp += (size_t)P * F;
  __half* f2h   = hp; hp += (size_t)M * F;
  __half* f3h   = hp; hp += (size_t)M * F;
  float* fp = (float*)hp;
  float* lat1f = fp; fp += (size_t)N1 * F;
  float* lat2f = fp; fp += (size_t)N2 * F;
  float* acc1  = fp; fp += (size_t)N1 * F;
  float* acc2  = fp; fp += (size_t)N2 * F;
  float* el    = fp; fp += (size_t)(2 * P + 2 * M) * H;
  float* er    = fp; fp += (size_t)(2 * P + 2 * M) * H;
  float* e0b   = fp; fp += (size_t)P * F;
  float* e1b   = fp; fp += (size_t)P * F;
  float* e2b   = fp; fp += (size_t)M * F;
  float* e3b   = fp; fp += (size_t)M * F;

  // ---- output layout: (simi_pm, d_gcn, med, m_gcn, patient) ----
  float* out_simi = (float*)d_out;               // P*M
  float* out_dgcn = out_simi + (size_t)P * M;    // DG*F
  float* out_med  = out_dgcn + (size_t)DG * F;   // M*F
  float* out_mgcn = out_med  + (size_t)M * F;    // M*F
  float* out_pat  = out_mgcn + (size_t)M * F;    // P*F

  // ---- zero padded counters (~540 KB) ----
  hipMemsetAsync(d_ws, 0, memset_bytes, stream);

  // ---- ELL build + fused fp16 embed cast: ONE dispatch ----
  int eb = ((HOE + 3) / 4 + 255) / 256;
  k_build<<<eb, 256, 0, stream>>>(adj1_rows, adj1_cols, adj1_vals,
                                  adj2_rows, adj2_cols, adj2_vals,
                                  g0_dst, g0_src, g1_dst, g1_src,
                                  g2_dst, g2_src, g3_dst, g3_src,
                                  cur1, ell1, cur2, ell2,
                                  cu0, eg0, cu1, eg1, cu2, eg2, cu3, eg3,
                                  ovf_n, ovf,
                                  pE, mE, dE, pEh, mEh, dEh);

  // ---- GNN: 2 layers, 1 wave per row (R9), XCD swizzle ----
  k_spmm<1><<<SPMM_NBLK, 256, 0, stream>>>(cur1, ell1, cur2, ell2, ovf_n, ovf,
                                           pEh, mEh, dEh, lat1f, lat2f, lat1h, lat2h,
                                           acc1, acc2, out_mgcn, out_dgcn);
  k_spmm<2><<<SPMM_NBLK, 256, 0, stream>>>(cur1, ell1, cur2, ell2, ovf_n, ovf,
                                           pEh, mEh, dEh, lat1f, lat2f, lat1h, lat2h,
                                           acc1, acc2, out_mgcn, out_dgcn);

  // ---- 4 GATs: scalar feature GEMM + 2-wave-split aggregation ----
  k_gat_feat_all<<<FEAT_BLOCKS, 256, 0, stream>>>(acc1, acc2, gat_W, gat_al, gat_ar,
                                                  f0h, f1h, f2h, f3h, el, er);
  int ab = (2 * P + 2 * M) / 2;   // 4300 groups * 128 threads / 256
  k_gat_agg_all<<<ab, 256, 0, stream>>>(cu0, eg0, cu1, eg1, cu2, eg2, cu3, eg3,
                                        ovf_n, ovf, el, er, f0h, f1h, f2h, f3h, gat_b,
                                        e0b, e1b, e2b, e3b);

  // ---- semantic attention weights ----
  k_sem_w_all<<<SEM_BLOCKS, 128, 0, stream>>>(e0b, e1b, e2b, e3b, sa_W1, sa_b1, sa_W2, wbuf);

  // ---- final: med+cvec+patient+simi fused (FIN_R=4, 500 blocks) ----
  k_final_all<<<P / FIN_R, 256, 0, stream>>>(e0b, e1b, e2b, e3b, wbuf, out_W, out_b,
                                             out_med, out_pat, out_simi);
}

// Round 10
// 295.848 us; speedup vs baseline: 1.1494x; 1.0118x over previous
//
#include <hip/hip_runtime.h>
#include <hip/hip_fp16.h>
#include <cmath>
#include <cstdint>

// Problem constants (fixed by the reference).
constexpr int P  = 2000, M = 150, DG = 2000, F = 256, H = 4, DH = 64;
constexpr int N1 = P + M;          // 2150
constexpr int N2 = P + DG;         // 4000
constexpr int E1 = 137600, E2 = 256000, EGP = 64000, EGM = 4800;
constexpr int SA_HID = 128;

// Edge-range offsets for the fused build kernel.
constexpr int HO1 = E1, HO2 = E1 + E2, HO3 = HO2 + EGP, HO4 = HO3 + EGP,
              HO5 = HO4 + EGM, HOE = HO5 + EGM;   // 531200 total edges

// ELL capacities (overflow list guarantees correctness regardless).
constexpr int CAP_A = 160;
constexpr int CAP_G = 96;
constexpr int OVF_CAP = 4096;

// One counter per 64B line (R7: removed same-line atomic serialization).
constexpr int CPAD = 16;

// ---- fp16 helpers -----------------------------------------------------------
__device__ __forceinline__ float4 h4_to_f4(const __half* p) {
  union { ushort4 u4; __half2 h2[2]; } u;
  u.u4 = *(const ushort4*)p;
  float2 lo = __half22float2(u.h2[0]);
  float2 hi = __half22float2(u.h2[1]);
  return make_float4(lo.x, lo.y, hi.x, hi.y);
}
__device__ __forceinline__ void f4_to_h4(__half* p, float4 v) {
  union { ushort4 u4; __half2 h2[2]; } u;
  u.h2[0] = __float22half2_rn(make_float2(v.x, v.y));
  u.h2[1] = __float22half2_rn(make_float2(v.z, v.w));
  *(ushort4*)p = u.u4;
}

// ---------------------------------------------------------------------------
// ELL build (padded counters) + fused fp32->fp16 embed cast.
// ---------------------------------------------------------------------------
constexpr int CAST_CH = (P * F + M * F + DG * F) / 8;   // 8-float chunks

__global__ __launch_bounds__(256) void k_build(
    const int* __restrict__ a1r, const int* __restrict__ a1c, const float* __restrict__ a1v,
    const int* __restrict__ a2r, const int* __restrict__ a2c, const float* __restrict__ a2v,
    const int* __restrict__ d0, const int* __restrict__ s0,
    const int* __restrict__ d1, const int* __restrict__ s1,
    const int* __restrict__ d2, const int* __restrict__ s2,
    const int* __restrict__ d3, const int* __restrict__ s3,
    int* cur1, uint2* ell1, int* cur2, uint2* ell2,
    int* cu0, unsigned* eg0, int* cu1, unsigned* eg1,
    int* cu2, unsigned* eg2, int* cu3, unsigned* eg3,
    int* __restrict__ ovf_n, int4* __restrict__ ovf,
    const float* __restrict__ pEf, const float* __restrict__ mEf,
    const float* __restrict__ dEf,
    __half* __restrict__ pEh, __half* __restrict__ mEh, __half* __restrict__ dEh) {
  int tid = blockIdx.x * 256 + threadIdx.x;
  int T = gridDim.x * 256;
  int seg[4], row[4]; unsigned p0[4], p1[4];
#pragma unroll
  for (int u = 0; u < 4; ++u) {
    int i = tid + u * T;
    seg[u] = -1;
    if (i < HOE) {
      if (i < HO1)      { seg[u] = 0; row[u] = a1r[i]; p0[u] = (unsigned)a1c[i]; p1[u] = __float_as_uint(a1v[i]); }
      else if (i < HO2) { int j = i - HO1; seg[u] = 1; row[u] = a2r[j]; p0[u] = (unsigned)a2c[j]; p1[u] = __float_as_uint(a2v[j]); }
      else if (i < HO3) { int j = i - HO2; seg[u] = 2; row[u] = d0[j]; p0[u] = (unsigned)s0[j]; }
      else if (i < HO4) { int j = i - HO3; seg[u] = 3; row[u] = d1[j]; p0[u] = (unsigned)s1[j]; }
      else if (i < HO5) { int j = i - HO4; seg[u] = 4; row[u] = d2[j]; p0[u] = (unsigned)s2[j]; }
      else              { int j = i - HO5; seg[u] = 5; row[u] = d3[j]; p0[u] = (unsigned)s3[j]; }
    }
  }
#pragma unroll
  for (int u = 0; u < 4; ++u) {
    int r = row[u];
    switch (seg[u]) {
      case 0: { int slot = atomicAdd(&cur1[(size_t)r * CPAD], 1);
        if (slot < CAP_A) ell1[(size_t)r * CAP_A + slot] = make_uint2(p0[u], p1[u]);
        else { int o = atomicAdd(&ovf_n[0], 1); if (o < OVF_CAP) ovf[0 * OVF_CAP + o] = make_int4(r, (int)p0[u], (int)p1[u], 0); } } break;
      case 1: { int slot = atomicAdd(&cur2[(size_t)r * CPAD], 1);
        if (slot < CAP_A) ell2[(size_t)r * CAP_A + slot] = make_uint2(p0[u], p1[u]);
        else { int o = atomicAdd(&ovf_n[1], 1); if (o < OVF_CAP) ovf[1 * OVF_CAP + o] = make_int4(r, (int)p0[u], (int)p1[u], 0); } } break;
      case 2: { int slot = atomicAdd(&cu0[(size_t)r * CPAD], 1);
        if (slot < CAP_G) eg0[(size_t)r * CAP_G + slot] = p0[u];
        else { int o = atomicAdd(&ovf_n[2], 1); if (o < OVF_CAP) ovf[2 * OVF_CAP + o] = make_int4(r, (int)p0[u], 0, 0); } } break;
      case 3: { int slot = atomicAdd(&cu1[(size_t)r * CPAD], 1);
        if (slot < CAP_G) eg1[(size_t)r * CAP_G + slot] = p0[u];
        else { int o = atomicAdd(&ovf_n[3], 1); if (o < OVF_CAP) ovf[3 * OVF_CAP + o] = make_int4(r, (int)p0[u], 0, 0); } } break;
      case 4: { int slot = atomicAdd(&cu2[(size_t)r * CPAD], 1);
        if (slot < CAP_G) eg2[(size_t)r * CAP_G + slot] = p0[u];
        else { int o = atomicAdd(&ovf_n[4], 1); if (o < OVF_CAP) ovf[4 * OVF_CAP + o] = make_int4(r, (int)p0[u], 0, 0); } } break;
      case 5: { int slot = atomicAdd(&cu3[(size_t)r * CPAD], 1);
        if (slot < CAP_G) eg3[(size_t)r * CAP_G + slot] = p0[u];
        else { int o = atomicAdd(&ovf_n[5], 1); if (o < OVF_CAP) ovf[5 * OVF_CAP + o] = make_int4(r, (int)p0[u], 0, 0); } } break;
      default: break;
    }
  }
  // Fused embed cast fp32 -> fp16 (independent streaming work).
  for (int c = tid; c < CAST_CH; c += T) {
    int j = c * 8;
    const float* src; __half* dst;
    if (j < P * F)              { src = pEf + j;               dst = pEh + j; }
    else if (j < P * F + M * F) { src = mEf + (j - P * F);     dst = mEh + (j - P * F); }
    else                        { src = dEf + (j - P*F - M*F); dst = dEh + (j - P*F - M*F); }
    float4 a = *(const float4*)src, b = *(const float4*)(src + 4);
    f4_to_h4(dst, a);
    f4_to_h4(dst + 4, b);
  }
}

// ---------------------------------------------------------------------------
// SPMM (R9, proven 299.3us): ONE wave per row (4 rows per 256-thread block).
// 8-edge in-flight gather batch, no barriers. XCD swizzle kept (free).
// ---------------------------------------------------------------------------
constexpr int SPMM_GROUPS = N1 + N2;                 // 6150
constexpr int SPMM_NBLK = (SPMM_GROUPS + 3) / 4;     // 1538
template<int LAYER>
__global__ __launch_bounds__(256) void k_spmm(
    const int* __restrict__ cur1, const uint2* __restrict__ ell1,
    const int* __restrict__ cur2, const uint2* __restrict__ ell2,
    const int* __restrict__ ovf_n, const int4* __restrict__ ovf,
    const __half* __restrict__ pEh, const __half* __restrict__ mEh,
    const __half* __restrict__ dEh,
    float* __restrict__ lat1f, float* __restrict__ lat2f,
    __half* __restrict__ lat1h, __half* __restrict__ lat2h,
    float* __restrict__ acc1, float* __restrict__ acc2,
    float* __restrict__ out_mgcn, float* __restrict__ out_dgcn) {
  // Bijective XCD swizzle (nb=1538, nb%8=2): XCD k gets a contiguous chunk.
  constexpr int Q = SPMM_NBLK / 8, Rr = SPMM_NBLK % 8;
  int xcd = blockIdx.x & 7, idx = blockIdx.x >> 3;
  int swz = (xcd < Rr) ? xcd * (Q + 1) + idx : Rr * (Q + 1) + (xcd - Rr) * Q + idx;
  int grp = swz * 4 + (threadIdx.x >> 6);            // row id (1 wave per row)
  if (grp >= SPMM_GROUPS) return;
  int lane = threadIdx.x & 63;
  bool g2 = grp >= N1;
  int row = g2 ? grp - N1 : grp;
  const uint2* pe = (g2 ? ell2 : ell1) + (size_t)row * CAP_A;
  const __half* latinh = g2 ? lat2h : lat1h;
  const __half* tailEh = g2 ? dEh : mEh;
  int deg = (g2 ? cur2 : cur1)[(size_t)row * CPAD];
  int dn = deg < CAP_A ? deg : CAP_A;
  int fo = lane << 2;
  float4 s = {0.f, 0.f, 0.f, 0.f};
  auto fetch = [&](int c) -> float4 {
    const __half* b;
    if (LAYER == 1) b = (c < P) ? (pEh + (size_t)c * F) : (tailEh + (size_t)(c - P) * F);
    else            b = latinh + (size_t)c * F;
    return h4_to_f4(b + fo);
  };
  int i = 0;
  for (; i + 8 <= dn; i += 8) {      // 8 edges in flight
    uint2 m[8]; float4 a[8];
#pragma unroll
    for (int u = 0; u < 8; ++u) m[u] = pe[i + u];
#pragma unroll
    for (int u = 0; u < 8; ++u) a[u] = fetch((int)m[u].x);
#pragma unroll
    for (int u = 0; u < 8; ++u) {
      float v = __uint_as_float(m[u].y);
      s.x += v * a[u].x; s.y += v * a[u].y; s.z += v * a[u].z; s.w += v * a[u].w;
    }
  }
  for (; i < dn; ++i) {
    uint2 m = pe[i];
    float v = __uint_as_float(m.y);
    float4 a = fetch((int)m.x);
    s.x += v * a.x; s.y += v * a.y; s.z += v * a.z; s.w += v * a.w;
  }
  // Overflow edges (normally zero).
  {
    int gi = g2 ? 1 : 0;
    int on = ovf_n[gi];
    if (on > 0) {
      const int4* ol = ovf + gi * OVF_CAP;
      for (int k = 0; k < on; ++k) {
        int4 e = ol[k];
        if (e.x == row) {
          float v = __int_as_float(e.z);
          float4 a = fetch(e.y);
          s.x += v * a.x; s.y += v * a.y; s.z += v * a.z; s.w += v * a.w;
        }
      }
    }
  }
  float4 l;
  l.x = s.x > 0.f ? s.x : 0.5f * s.x;
  l.y = s.y > 0.f ? s.y : 0.5f * s.y;
  l.z = s.z > 0.f ? s.z : 0.5f * s.z;
  l.w = s.w > 0.f ? s.w : 0.5f * s.w;
  if (LAYER == 1) {
    *(float4*)((g2 ? lat2f : lat1f) + (size_t)row * F + fo) = l;   // exact own-row
    f4_to_h4((g2 ? lat2h : lat1h) + (size_t)row * F + fo, l);      // gather copy
  } else {
    const float* latf = g2 ? lat2f : lat1f;
    float4 b = *(const float4*)(latf + (size_t)row * F + fo);
    float4 a = {b.x + l.x, b.y + l.y, b.z + l.z, b.w + l.w};
    *(float4*)((g2 ? acc2 : acc1) + (size_t)row * F + fo) = a;
    if (row >= P)
      *(float4*)((g2 ? out_dgcn : out_mgcn) + (size_t)(row - P) * F + fo) = a;
  }
}

// ---------------------------------------------------------------------------
// All 4 GAT feature GEMMs. FR=8 (R8/R9: occupancy beats W-traffic reduction).
// ---------------------------------------------------------------------------
constexpr int FR  = 8;
constexpr int NB0 = (P + FR - 1) / FR;   // 250
constexpr int NB2 = (M + FR - 1) / FR;   // 19
constexpr int FEAT_BLOCKS = 2 * NB0 + 2 * NB2;

__global__ __launch_bounds__(256) void k_gat_feat_all(
    const float* __restrict__ acc1, const float* __restrict__ acc2,
    const float* __restrict__ gat_W, const float* __restrict__ gat_al,
    const float* __restrict__ gat_ar,
    __half* __restrict__ f0, __half* __restrict__ f1,
    __half* __restrict__ f2, __half* __restrict__ f3,
    float* __restrict__ el, float* __restrict__ er) {
  int b = blockIdx.x;
  int g, rb, n; const float* h; __half* fout;
  if (b < NB0)            { g = 0; rb = b;              n = P; h = acc1; fout = f0; }
  else if (b < 2 * NB0)   { g = 1; rb = b - NB0;        n = P; h = acc2; fout = f1; }
  else if (b < 2*NB0+NB2) { g = 2; rb = b - 2 * NB0;    n = M; h = acc1 + (size_t)P * F; fout = f2; }
  else                    { g = 3; rb = b - 2*NB0 - NB2; n = M; h = acc1 + (size_t)P * F; fout = f3; }
  int elo = (g == 0) ? 0 : (g == 1) ? P * H : (g == 2) ? 2 * P * H : (2 * P + M) * H;
  const float* W = gat_W + (size_t)g * F * F;
  __shared__ float hs[FR][F];
  int t = threadIdx.x;
  int r0 = rb * FR;
  for (int q = t; q < FR * 64; q += 256) {
    int r = q >> 6, ln = q & 63;
    int row = r0 + r;
    float4 v = {0.f, 0.f, 0.f, 0.f};
    if (row < n) v = *(const float4*)(h + (size_t)row * F + (ln << 2));
    *(float4*)&hs[r][ln << 2] = v;
  }
  __syncthreads();
  float acc[FR];
#pragma unroll
  for (int r = 0; r < FR; ++r) acc[r] = 0.f;
  for (int k = 0; k < F; k += 4) {
    float w0 = W[(size_t)k * F + t],       w1 = W[(size_t)(k + 1) * F + t],
          w2 = W[(size_t)(k + 2) * F + t], w3 = W[(size_t)(k + 3) * F + t];
#pragma unroll
    for (int r = 0; r < FR; ++r) {
      float4 h4 = *(const float4*)&hs[r][k];
      acc[r] += h4.x * w0 + h4.y * w1 + h4.z * w2 + h4.w * w3;
    }
  }
  int head = t >> 6, d = t & 63;           // one wave == one head
  float av = gat_al[g * H * DH + head * DH + d];
  float rv = gat_ar[g * H * DH + head * DH + d];
#pragma unroll
  for (int r = 0; r < FR; ++r) {
    int row = r0 + r;
    if (row < n) {
      fout[(size_t)row * F + t] = __float2half_rn(acc[r]);
      float cl = acc[r] * av, cr = acc[r] * rv;
      for (int o = 32; o > 0; o >>= 1) {
        cl += __shfl_down(cl, o, 64);
        cr += __shfl_down(cr, o, 64);
      }
      if (d == 0) { el[elo + row * H + head] = cl; er[elo + row * H + head] = cr; }
    }
  }
}

// ---------------------------------------------------------------------------
// All 4 GAT aggregations (R10): ONE wave per dst-row (4 rows per block) —
// same mechanism as the R9 spmm win: ~32 edges/row means the old 2-wave
// parity split gave each wave only ~2 deep-loop iterations then paid 2 LDS
// merge rounds + 2 barriers with wave-1 idle in the epilogue. Now: zero
// barriers, zero LDS, 8 loads in flight per pass, all lanes write.
// ---------------------------------------------------------------------------
constexpr int AGG_GROUPS = 2 * P + 2 * M;   // 4300
constexpr int AGG_NBLK = AGG_GROUPS / 4;    // 1075
__global__ __launch_bounds__(256) void k_gat_agg_all(
    const int* __restrict__ cu0, const unsigned* __restrict__ eg0,
    const int* __restrict__ cu1, const unsigned* __restrict__ eg1,
    const int* __restrict__ cu2, const unsigned* __restrict__ eg2,
    const int* __restrict__ cu3, const unsigned* __restrict__ eg3,
    const int* __restrict__ ovf_n, const int4* __restrict__ ovf,
    const float* __restrict__ el, const float* __restrict__ er,
    const __half* __restrict__ f0, const __half* __restrict__ f1,
    const __half* __restrict__ f2, const __half* __restrict__ f3,
    const float* __restrict__ gat_b,
    float* __restrict__ e0, float* __restrict__ e1,
    float* __restrict__ e2, float* __restrict__ e3) {
  int grp = blockIdx.x * 4 + (threadIdx.x >> 6);
  int lane = threadIdx.x & 63;
  int g, row; const int* cu; const unsigned* eg; const __half* feat; float* out; int elo;
  if (grp < P)            { g = 0; row = grp;             cu = cu0; eg = eg0; feat = f0; out = e0; elo = 0; }
  else if (grp < 2 * P)   { g = 1; row = grp - P;         cu = cu1; eg = eg1; feat = f1; out = e1; elo = P * H; }
  else if (grp < 2*P + M) { g = 2; row = grp - 2 * P;     cu = cu2; eg = eg2; feat = f2; out = e2; elo = 2 * P * H; }
  else                    { g = 3; row = grp - 2 * P - M; cu = cu3; eg = eg3; feat = f3; out = e3; elo = (2 * P + M) * H; }
  int head = lane >> 4;
  int fo = lane << 2;
  const float* elb = el + elo;
  float erv = er[elo + row * H + head];
  int deg = cu[(size_t)row * CPAD];
  int dn = deg < CAP_G ? deg : CAP_G;
  const unsigned* ps = eg + (size_t)row * CAP_G;
  int on = ovf_n[2 + g];
  const int4* ol = ovf + (2 + g) * OVF_CAP;
  // ---- pass 1: max over the whole row, 8 score loads in flight ----
  float mx = -3.4e38f;
  int i = 0;
  for (; i + 8 <= dn; i += 8) {
    int sx[8]; float vv[8];
#pragma unroll
    for (int u = 0; u < 8; ++u) sx[u] = (int)ps[i + u];
#pragma unroll
    for (int u = 0; u < 8; ++u) vv[u] = elb[sx[u] * H + head] + erv;
#pragma unroll
    for (int u = 0; u < 8; ++u) { float a = vv[u]; a = a > 0.f ? a : 0.2f * a; mx = fmaxf(mx, a); }
  }
  for (; i < dn; ++i) {
    float a = elb[(int)ps[i] * H + head] + erv;
    a = a > 0.f ? a : 0.2f * a;
    mx = fmaxf(mx, a);
  }
  if (on > 0) {
    for (int k = 0; k < on; ++k) {
      int4 e = ol[k];
      if (e.x == row) {
        float a = elb[e.y * H + head] + erv;
        a = a > 0.f ? a : 0.2f * a;
        mx = fmaxf(mx, a);
      }
    }
  }
  // ---- pass 2: exp-sum + weighted aggregation, 8 gathers in flight ----
  float ssum = 0.f;
  float4 acc = {0.f, 0.f, 0.f, 0.f};
  i = 0;
  for (; i + 8 <= dn; i += 8) {
    int sx[8]; float xs[8]; float4 q[8];
#pragma unroll
    for (int u = 0; u < 8; ++u) sx[u] = (int)ps[i + u];
#pragma unroll
    for (int u = 0; u < 8; ++u) q[u] = h4_to_f4(feat + (size_t)sx[u] * F + fo);
#pragma unroll
    for (int u = 0; u < 8; ++u) {
      float a = elb[sx[u] * H + head] + erv; a = a > 0.f ? a : 0.2f * a;
      xs[u] = expf(a - mx);
    }
#pragma unroll
    for (int u = 0; u < 8; ++u) {
      ssum += xs[u];
      acc.x += xs[u] * q[u].x; acc.y += xs[u] * q[u].y;
      acc.z += xs[u] * q[u].z; acc.w += xs[u] * q[u].w;
    }
  }
  for (; i < dn; ++i) {
    int s0 = (int)ps[i];
    float a = elb[s0 * H + head] + erv; a = a > 0.f ? a : 0.2f * a;
    float x0 = expf(a - mx);
    float4 q0 = h4_to_f4(feat + (size_t)s0 * F + fo);
    ssum += x0;
    acc.x += x0 * q0.x; acc.y += x0 * q0.y; acc.z += x0 * q0.z; acc.w += x0 * q0.w;
  }
  if (on > 0) {
    for (int k = 0; k < on; ++k) {
      int4 e = ol[k];
      if (e.x == row) {
        float a = elb[e.y * H + head] + erv; a = a > 0.f ? a : 0.2f * a;
        float x0 = expf(a - mx);
        float4 q0 = h4_to_f4(feat + (size_t)e.y * F + fo);
        ssum += x0;
        acc.x += x0 * q0.x; acc.y += x0 * q0.y; acc.z += x0 * q0.z; acc.w += x0 * q0.w;
      }
    }
  }
  float inv = 1.f / (ssum + 1e-9f);
  const float* bb = gat_b + g * F + fo;
  float4 v = {acc.x * inv + bb[0], acc.y * inv + bb[1],
              acc.z * inv + bb[2], acc.w * inv + bb[3]};
  v.x = v.x > 0.f ? v.x : expm1f(v.x);
  v.y = v.y > 0.f ? v.y : expm1f(v.y);
  v.z = v.z > 0.f ? v.z : expm1f(v.z);
  v.w = v.w > 0.f ? v.w : expm1f(v.w);
  *(float4*)(out + (size_t)row * F + fo) = v;
}

// ---------------------------------------------------------------------------
// Semantic attention weights. SR=4; R10: k-loop unrolled x2 -> 8 W1 loads in
// flight per iteration (deeper MLP on the dominant load stream).
// ---------------------------------------------------------------------------
constexpr int SR  = 4;
constexpr int SB0 = (P + SR - 1) / SR;   // 500
constexpr int SB2 = (M + SR - 1) / SR;   // 38
constexpr int SEM_BLOCKS = 2 * SB0 + 2 * SB2;

__global__ __launch_bounds__(128) void k_sem_w_all(
    const float* __restrict__ e0, const float* __restrict__ e1,
    const float* __restrict__ e2, const float* __restrict__ e3,
    const float* __restrict__ W1, const float* __restrict__ b1,
    const float* __restrict__ W2, float* __restrict__ w) {
  int b = blockIdx.x;
  int zid, rb, n; const float* z;
  if (b < SB0)            { zid = 0; rb = b;             n = P; z = e0; }
  else if (b < 2 * SB0)   { zid = 1; rb = b - SB0;       n = P; z = e1; }
  else if (b < 2*SB0+SB2) { zid = 2; rb = b - 2 * SB0;   n = M; z = e2; }
  else                    { zid = 3; rb = b - 2*SB0-SB2; n = M; z = e3; }
  __shared__ float zs[SR][F];
  int t = threadIdx.x;
  int r0 = rb * SR;
  for (int q = t; q < SR * 64; q += 128) {
    int r = q >> 6, ln = q & 63;
    int row = r0 + r;
    float4 v = {0.f, 0.f, 0.f, 0.f};
    if (row < n) v = *(const float4*)(z + (size_t)row * F + (ln << 2));
    *(float4*)&zs[r][ln << 2] = v;
  }
  __syncthreads();
  float hid[SR];
#pragma unroll
  for (int r = 0; r < SR; ++r) hid[r] = b1[t];
  for (int k = 0; k < F; k += 8) {
    float w0 = W1[(size_t)k * SA_HID + t],       w1 = W1[(size_t)(k + 1) * SA_HID + t],
          w2 = W1[(size_t)(k + 2) * SA_HID + t], w3 = W1[(size_t)(k + 3) * SA_HID + t];
    float w4 = W1[(size_t)(k + 4) * SA_HID + t], w5 = W1[(size_t)(k + 5) * SA_HID + t],
          w6 = W1[(size_t)(k + 6) * SA_HID + t], w7 = W1[(size_t)(k + 7) * SA_HID + t];
#pragma unroll
    for (int r = 0; r < SR; ++r) {
      float4 za = *(const float4*)&zs[r][k];
      float4 zb = *(const float4*)&zs[r][k + 4];
      hid[r] += za.x * w0 + za.y * w1 + za.z * w2 + za.w * w3
              + zb.x * w4 + zb.y * w5 + zb.z * w6 + zb.w * w7;
    }
  }
  float w2v = W2[t];
  float local = 0.f;
  for (int r = 0; r < SR; ++r) {
    int row = r0 + r;
    if (row < n) local += tanhf(hid[r]) * w2v;
  }
  for (int o = 32; o > 0; o >>= 1) local += __shfl_down(local, o, 64);
  __shared__ float pp[2];
  if ((t & 63) == 0) pp[t >> 6] = local;
  __syncthreads();
  if (t == 0) atomicAdd(&w[zid], pp[0] + pp[1]);
}

// ---------------------------------------------------------------------------
// Final (R5 form, proven): FIN_R=4 -> 500 blocks (2/CU); patient loads issued
// first; med loop unrolled x2; cvec fused into the simi GEMM f-loop.
// ---------------------------------------------------------------------------
constexpr int FIN_R = 4;   // P % FIN_R == 0 -> 500 blocks
__global__ __launch_bounds__(256) void k_final_all(
    const float* __restrict__ e0, const float* __restrict__ e1,
    const float* __restrict__ e2, const float* __restrict__ e3,
    const float* __restrict__ w, const float* __restrict__ outW,
    const float* __restrict__ outb,
    float* __restrict__ out_med, float* __restrict__ out_pat,
    float* __restrict__ simi) {
  int t = threadIdx.x;
  // betas
  float mm0 = w[2] * (1.f / M), mm1 = w[3] * (1.f / M);
  float mmx = fmaxf(mm0, mm1);
  float bm0 = expf(mm0 - mmx), bm1 = expf(mm1 - mmx);
  float msc = 1.f / (bm0 + bm1);
  bm0 *= msc; bm1 *= msc;
  float pm0 = w[0] * (1.f / P), pm1 = w[1] * (1.f / P);
  float pmx = fmaxf(pm0, pm1);
  float bp0 = expf(pm0 - pmx), bp1 = expf(pm1 - pmx);
  float psc = 1.f / (bp0 + bp1);
  bp0 *= psc; bp1 *= psc;
  // ---- patient rows: issue loads FIRST (FIN_R*64 == 256 -> one per thread) --
  int r0 = blockIdx.x * FIN_R;
  int pr = t >> 6, pln = t & 63;
  size_t poff = (size_t)(r0 + pr) * F + (pln << 2);
  float4 pu0 = *(const float4*)(e0 + poff);
  float4 pu1 = *(const float4*)(e1 + poff);
  // ---- med combine + relu col-sum, unrolled x2 (4 loads in flight) ----
  constexpr int MED4 = M * F / 4;   // 9600
  float4 rs = {0.f, 0.f, 0.f, 0.f};
  bool wr_med = (blockIdx.x == 0);
  for (int j = t; j < MED4; j += 512) {
    float4 u0 = ((const float4*)e2)[j], u1 = ((const float4*)e3)[j];
    float4 v0, v1;
    bool second = (j + 256) < MED4;
    if (second) { v0 = ((const float4*)e2)[j + 256]; v1 = ((const float4*)e3)[j + 256]; }
    float4 r = {bm0 * u0.x + bm1 * u1.x, bm0 * u0.y + bm1 * u1.y,
                bm0 * u0.z + bm1 * u1.z, bm0 * u0.w + bm1 * u1.w};
    if (wr_med) ((float4*)out_med)[j] = r;
    rs.x += r.x > 0.f ? r.x : 0.f;
    rs.y += r.y > 0.f ? r.y : 0.f;
    rs.z += r.z > 0.f ? r.z : 0.f;
    rs.w += r.w > 0.f ? r.w : 0.f;
    if (second) {
      float4 r2 = {bm0 * v0.x + bm1 * v1.x, bm0 * v0.y + bm1 * v1.y,
                   bm0 * v0.z + bm1 * v1.z, bm0 * v0.w + bm1 * v1.w};
      if (wr_med) ((float4*)out_med)[j + 256] = r2;
      rs.x += r2.x > 0.f ? r2.x : 0.f;
      rs.y += r2.y > 0.f ? r2.y : 0.f;
      rs.z += r2.z > 0.f ? r2.z : 0.f;
      rs.w += r2.w > 0.f ? r2.w : 0.f;
    }
  }
  // ---- patient combine written to LDS + out_pat (before sv barriers) ----
  __shared__ float psh[FIN_R][F];
  {
    float4 v = {bp0 * pu0.x + bp1 * pu1.x, bp0 * pu0.y + bp1 * pu1.y,
                bp0 * pu0.z + bp1 * pu1.z, bp0 * pu0.w + bp1 * pu1.w};
    *(float4*)(out_pat + poff) = v;
    v.x = v.x > 0.f ? v.x : 0.f; v.y = v.y > 0.f ? v.y : 0.f;
    v.z = v.z > 0.f ? v.z : 0.f; v.w = v.w > 0.f ? v.w : 0.f;
    *(float4*)&psh[pr][pln << 2] = v;
  }
  // ---- sv reduce (barriers also publish psh) ----
  __shared__ float4 sv4[4][64];
  sv4[t >> 6][t & 63] = rs;
  __syncthreads();
  __shared__ float sv[F];
  if (t < 64) {
    float4 a = sv4[0][t], b = sv4[1][t], c = sv4[2][t], d = sv4[3][t];
    sv[t * 4 + 0] = a.x + b.x + c.x + d.x;
    sv[t * 4 + 1] = a.y + b.y + c.y + d.y;
    sv[t * 4 + 2] = a.z + b.z + c.z + d.z;
    sv[t * 4 + 3] = a.w + b.w + c.w + d.w;
  }
  __syncthreads();
  // ---- fused cvec + simi GEMM: 8 outW loads, 5 acc chains per f-step ----
  if (t < M) {
    float acc[FIN_R];
#pragma unroll
    for (int r = 0; r < FIN_R; ++r) acc[r] = 0.f;
    float cv = (float)M * outb[t];
    for (int f = 0; f < F; f += 4) {
      float w0 = outW[(size_t)f * M + t],       w1 = outW[(size_t)(f + 1) * M + t],
            w2 = outW[(size_t)(f + 2) * M + t], w3 = outW[(size_t)(f + 3) * M + t];
      float b0 = outW[(size_t)(F + f) * M + t],     b1 = outW[(size_t)(F + f + 1) * M + t],
            b2 = outW[(size_t)(F + f + 2) * M + t], b3 = outW[(size_t)(F + f + 3) * M + t];
      cv += sv[f] * b0 + sv[f + 1] * b1 + sv[f + 2] * b2 + sv[f + 3] * b3;
#pragma unroll
      for (int r = 0; r < FIN_R; ++r) {
        float4 p4 = *(const float4*)&psh[r][f];
        acc[r] += p4.x * w0 + p4.y * w1 + p4.z * w2 + p4.w * w3;
      }
    }
#pragma unroll
    for (int r = 0; r < FIN_R; ++r)
      simi[(size_t)(r0 + r) * M + t] = (float)M * acc[r] + cv;
  }
}

// ---------------------------------------------------------------------------
extern "C" void kernel_launch(void* const* d_in, const int* in_sizes, int n_in,
                              void* d_out, int out_size, void* d_ws, size_t ws_size,
                              hipStream_t stream) {
  const int*   adj1_rows = (const int*)d_in[0];
  const int*   adj1_cols = (const int*)d_in[1];
  const float* adj1_vals = (const float*)d_in[2];
  const int*   adj2_rows = (const int*)d_in[3];
  const int*   adj2_cols = (const int*)d_in[4];
  const float* adj2_vals = (const float*)d_in[5];
  const int*   g0_src = (const int*)d_in[6];
  const int*   g0_dst = (const int*)d_in[7];
  const int*   g1_src = (const int*)d_in[8];
  const int*   g1_dst = (const int*)d_in[9];
  const int*   g2_src = (const int*)d_in[10];
  const int*   g2_dst = (const int*)d_in[11];
  const int*   g3_src = (const int*)d_in[12];
  const int*   g3_dst = (const int*)d_in[13];
  // d_in[14] = keepRate (unused, == 1)
  const float* pE     = (const float*)d_in[15];
  const float* mE     = (const float*)d_in[16];
  const float* dE     = (const float*)d_in[17];
  const float* gat_W  = (const float*)d_in[18];
  const float* gat_al = (const float*)d_in[19];
  const float* gat_ar = (const float*)d_in[20];
  const float* gat_b  = (const float*)d_in[21];
  const float* sa_W1  = (const float*)d_in[22];
  const float* sa_b1  = (const float*)d_in[23];
  const float* sa_W2  = (const float*)d_in[24];
  const float* out_W  = (const float*)d_in[25];
  const float* out_b  = (const float*)d_in[26];

  // ---- workspace layout: [zeroed (padded counters) | ELL | fp16 | fp32] ----
  int* ip = (int*)d_ws;
  int* cur1 = ip; ip += (size_t)N1 * CPAD;
  int* cur2 = ip; ip += (size_t)N2 * CPAD;
  int* cu0  = ip; ip += (size_t)P * CPAD;
  int* cu1  = ip; ip += (size_t)P * CPAD;
  int* cu2  = ip; ip += (size_t)M * CPAD;
  int* cu3  = ip; ip += (size_t)M * CPAD;
  int* ovf_n = ip; ip += 6;
  float* wbuf = (float*)ip; ip += 4;
  size_t memset_bytes = (size_t)((char*)ip - (char*)d_ws);

  uintptr_t up = ((uintptr_t)ip + 15) & ~(uintptr_t)15;
  int4* ovf = (int4*)up;                       // 6 * OVF_CAP
  uint2* ell1 = (uint2*)(ovf + 6 * OVF_CAP);   // N1 * CAP_A
  uint2* ell2 = ell1 + (size_t)N1 * CAP_A;     // N2 * CAP_A
  unsigned* eg0 = (unsigned*)(ell2 + (size_t)N2 * CAP_A);
  unsigned* eg1 = eg0 + (size_t)P * CAP_G;
  unsigned* eg2 = eg1 + (size_t)P * CAP_G;
  unsigned* eg3 = eg2 + (size_t)M * CAP_G;
  // fp16 region (16B-aligned by construction)
  __half* hp = (__half*)(eg3 + (size_t)M * CAP_G);
  __half* pEh   = hp; hp += (size_t)P * F;
  __half* mEh   = hp; hp += (size_t)M * F;
  __half* dEh   = hp; hp += (size_t)DG * F;
  __half* lat1h = hp; hp += (size_t)N1 * F;
  __half* lat2h = hp; hp += (size_t)N2 * F;
  __half* f0h   = hp; hp += (size_t)P * F;
  __half* f1h   = hp; hp += (size_t)P * F;
  __half* f2h   = hp; hp += (size_t)M * F;
  __half* f3h   = hp; hp += (size_t)M * F;
  float* fp = (float*)hp;
  float* lat1f = fp; fp += (size_t)N1 * F;
  float* lat2f = fp; fp += (size_t)N2 * F;
  float* acc1  = fp; fp += (size_t)N1 * F;
  float* acc2  = fp; fp += (size_t)N2 * F;
  float* el    = fp; fp += (size_t)(2 * P + 2 * M) * H;
  float* er    = fp; fp += (size_t)(2 * P + 2 * M) * H;
  float* e0b   = fp; fp += (size_t)P * F;
  float* e1b   = fp; fp += (size_t)P * F;
  float* e2b   = fp; fp += (size_t)M * F;
  float* e3b   = fp; fp += (size_t)M * F;

  // ---- output layout: (simi_pm, d_gcn, med, m_gcn, patient) ----
  float* out_simi = (float*)d_out;               // P*M
  float* out_dgcn = out_simi + (size_t)P * M;    // DG*F
  float* out_med  = out_dgcn + (size_t)DG * F;   // M*F
  float* out_mgcn = out_med  + (size_t)M * F;    // M*F
  float* out_pat  = out_mgcn + (size_t)M * F;    // P*F

  // ---- zero padded counters (~540 KB) ----
  hipMemsetAsync(d_ws, 0, memset_bytes, stream);

  // ---- ELL build + fused fp16 embed cast: ONE dispatch ----
  int eb = ((HOE + 3) / 4 + 255) / 256;
  k_build<<<eb, 256, 0, stream>>>(adj1_rows, adj1_cols, adj1_vals,
                                  adj2_rows, adj2_cols, adj2_vals,
                                  g0_dst, g0_src, g1_dst, g1_src,
                                  g2_dst, g2_src, g3_dst, g3_src,
                                  cur1, ell1, cur2, ell2,
                                  cu0, eg0, cu1, eg1, cu2, eg2, cu3, eg3,
                                  ovf_n, ovf,
                                  pE, mE, dE, pEh, mEh, dEh);

  // ---- GNN: 2 layers, 1 wave per row (R9), XCD swizzle ----
  k_spmm<1><<<SPMM_NBLK, 256, 0, stream>>>(cur1, ell1, cur2, ell2, ovf_n, ovf,
                                           pEh, mEh, dEh, lat1f, lat2f, lat1h, lat2h,
                                           acc1, acc2, out_mgcn, out_dgcn);
  k_spmm<2><<<SPMM_NBLK, 256, 0, stream>>>(cur1, ell1, cur2, ell2, ovf_n, ovf,
                                           pEh, mEh, dEh, lat1f, lat2f, lat1h, lat2h,
                                           acc1, acc2, out_mgcn, out_dgcn);

  // ---- 4 GATs: scalar feature GEMM + 1-wave-per-row aggregation (R10) ----
  k_gat_feat_all<<<FEAT_BLOCKS, 256, 0, stream>>>(acc1, acc2, gat_W, gat_al, gat_ar,
                                                  f0h, f1h, f2h, f3h, el, er);
  k_gat_agg_all<<<AGG_NBLK, 256, 0, stream>>>(cu0, eg0, cu1, eg1, cu2, eg2, cu3, eg3,
                                              ovf_n, ovf, el, er, f0h, f1h, f2h, f3h, gat_b,
                                              e0b, e1b, e2b, e3b);

  // ---- semantic attention weights ----
  k_sem_w_all<<<SEM_BLOCKS, 128, 0, stream>>>(e0b, e1b, e2b, e3b, sa_W1, sa_b1, sa_W2, wbuf);

  // ---- final: med+cvec+patient+simi fused (FIN_R=4, 500 blocks) ----
  k_final_all<<<P / FIN_R, 256, 0, stream>>>(e0b, e1b, e2b, e3b, wbuf, out_W, out_b,
                                             out_med, out_pat, out_simi);
}